// Round 1
// baseline (1289.762 us; speedup 1.0000x reference)
//
#include <hip/hip_runtime.h>
#include <math.h>

#define A0_INV (1.0f/0.529177249f)

__device__ __constant__ float c_SIGMA[8] = {
    0.5515909f, 1.8886297f, 1.3225029f, 1.2316629f,
    2.1884933f, 1.7750372f, 1.3677907f, 1.3820058f};

__device__ inline float celu01(float x) {
    return x > 0.0f ? x : 0.1f * expm1f(x * 10.0f);
}
__device__ inline float softplusf_(float x) {
    return fmaxf(x, 0.0f) + log1pf(expf(-fabsf(x)));
}

// One dense layer over a 32-atom tile. sIn packed [a*K+k], weights row-major
// (K, OUT). Thread t < OUT owns output column t, accumulates all 32 atoms in
// registers (16 FMA per weight load; sIn reads are wave-broadcast, no bank
// conflicts).
template<int K, int OUT, bool CELU>
__device__ inline void dense_tile(const float* __restrict__ sIn,
                                  const float* __restrict__ W,
                                  const float* __restrict__ b,
                                  float* __restrict__ sOut, int t)
{
    if (t < OUT) {
        float acc[32];
#pragma unroll
        for (int a = 0; a < 32; ++a) acc[a] = 0.0f;
#pragma unroll 2
        for (int k = 0; k < K; ++k) {
            float w = W[k * OUT + t];
#pragma unroll
            for (int a = 0; a < 32; ++a)
                acc[a] = fmaf(sIn[a * K + k], w, acc[a]);
        }
        float bb = b[t];
#pragma unroll
        for (int a = 0; a < 32; ++a) {
            float v = acc[a] + bb;
            sOut[a * OUT + t] = CELU ? celu01(v) : v;
        }
    }
}

// ---------------- Phase 1: chi MLP (shared weights), 32 atoms / block ------
__global__ __launch_bounds__(256) void chi_kernel(
    const float* __restrict__ aev, const int* __restrict__ species,
    const float* __restrict__ W1, const float* __restrict__ b1,
    const float* __restrict__ W2, const float* __restrict__ b2,
    const float* __restrict__ W3, const float* __restrict__ b3,
    const float* __restrict__ W4, const float* __restrict__ b4,
    float* __restrict__ chi_out)
{
    __shared__ float smem[12288 + 5120];   // 68 KB -> 2 blocks/CU
    float* sA  = smem;           // [32][384]
    float* sH1 = smem + 12288;   // [32][160]
    float* sH2 = smem;           // [32][128]  (aliases dead sA)
    float* sH3 = smem + 4096;    // [32][96]
    const int t = threadIdx.x;
    const long base = (long)blockIdx.x * 32;

    for (int i = t; i < 32 * 384; i += 256)
        sA[i] = aev[base * 384 + i];
    __syncthreads();
    dense_tile<384, 160, true>(sA,  W1, b1, sH1, t);
    __syncthreads();
    dense_tile<160, 128, true>(sH1, W2, b2, sH2, t);
    __syncthreads();
    dense_tile<128,  96, true>(sH2, W3, b3, sH3, t);
    __syncthreads();
    if (t < 32) {
        float acc = 0.0f;
#pragma unroll
        for (int u = 0; u < 96; ++u) acc = fmaf(sH3[t * 96 + u], W4[u], acc);
        float chi = softplusf_(acc + b4[0]);
        int atom = (int)base + t;
        if (species[atom] == -1) chi = 0.0f;
        chi_out[atom] = chi;
    }
}

// ---------------- Phase 2: per-molecule q / ESP / coulomb ------------------
__global__ __launch_bounds__(64) void mol_kernel(
    const int* __restrict__ species, const float* __restrict__ coords,
    const float* __restrict__ netq, const float* __restrict__ chi,
    float* __restrict__ qv, float* __restrict__ esp, float* __restrict__ coul,
    float* __restrict__ o_species, float* __restrict__ o_q)
{
    const int m = blockIdx.x, j = threadIdx.x;
    const int atom = m * 64 + j;
    __shared__ float sx[64], sy[64], sz[64], sq[64], ss2[64];

    int s = species[atom];
    float pad = (s != -1) ? 1.0f : 0.0f;
    float chij = chi[atom];

    float cs = chij, na = pad;
#pragma unroll
    for (int o = 32; o > 0; o >>= 1) {
        cs += __shfl_xor(cs, o);
        na += __shfl_xor(na, o);
    }
    float qc = netq[m];
    float k_net = 1.0f + fabsf(qc) / cs;
    float chi_mean = cs / na;
    float k_p = (qc > 0.0f) ? k_net : 1.0f;
    float k_n = (qc < 0.0f) ? k_net : 1.0f;
    float qj = (-k_n * chij + k_p * chi_mean) * pad;

    float sg = c_SIGMA[s < 0 ? 0 : s];
    float x = coords[atom * 3 + 0], y = coords[atom * 3 + 1], z = coords[atom * 3 + 2];
    sx[j] = x; sy[j] = y; sz[j] = z; sq[j] = qj; ss2[j] = sg * sg;
    __syncthreads();

    float s2j = sg * sg;
    float ej = 0.0f;
    for (int i = 0; i < 64; ++i) {
        if (i == j) continue;
        float dx = sx[i] - x, dy = sy[i] - y, dz = sz[i] - z;
        float d = sqrtf(dx * dx + dy * dy + dz * dz + 1e-16f) * A0_INV;
        float ssum = fmaxf(ss2[i] + s2j, 1e-8f);
        float jij = erff(d * rsqrtf(2.0f * ssum)) / d;
        ej = fmaf(sq[i], jij, ej);
    }
    ej *= pad;

    float ce = qj * ej;
#pragma unroll
    for (int o = 32; o > 0; o >>= 1) ce += __shfl_xor(ce, o);
    if (j == 0) coul[m] = 0.5f * ce;

    qv[atom] = qj;
    esp[atom] = ej;
    o_species[atom] = (float)s;
    o_q[atom] = qj;
}

// ---------------- Phase 3: species bucketing -------------------------------
__global__ void init_kernel(int* counts, int* cursors) {
    int t = threadIdx.x;
    if (t < 8) { counts[t] = 0; cursors[t] = 0; }
}
__global__ void count_kernel(const int* __restrict__ species, int* counts,
                             float* __restrict__ outat, int A) {
    int a = blockIdx.x * 256 + threadIdx.x;
    if (a < A) {
        outat[a] = 0.0f;                 // zero-init routed output (invalid atoms stay 0)
        int s = species[a];
        if (s >= 0) atomicAdd(&counts[s], 1);
    }
}
__global__ void scan_kernel(const int* counts, int* offs) {
    offs[0] = 0;
    for (int e = 0; e < 8; ++e) offs[e + 1] = offs[e] + counts[e];
}
__global__ void fill_kernel(const int* __restrict__ species, const int* offs,
                            int* cursors, int* bidx, int A) {
    int a = blockIdx.x * 256 + threadIdx.x;
    if (a < A) {
        int s = species[a];
        if (s >= 0) {
            int pos = offs[s] + atomicAdd(&cursors[s], 1);
            bidx[pos] = a;
        }
    }
}

// ---------------- Phase 4: routed expert MLP, 32 atoms / block -------------
__global__ __launch_bounds__(256) void expert_kernel(
    const float* __restrict__ aev, const float* __restrict__ qv,
    const float* __restrict__ esp,
    const float* __restrict__ W1, const float* __restrict__ b1,
    const float* __restrict__ W2, const float* __restrict__ b2,
    const float* __restrict__ W3, const float* __restrict__ b3,
    const float* __restrict__ W4, const float* __restrict__ b4,
    const int* __restrict__ counts, const int* __restrict__ offs,
    const int* __restrict__ bidx, float* __restrict__ outat, int tilesMax)
{
    const int e = blockIdx.x / tilesMax;
    const int tile = blockIdx.x - e * tilesMax;
    const int cnt = counts[e];
    const int start = tile * 32;
    if (start >= cnt) return;
    const int nA = min(32, cnt - start);

    __shared__ float smem[12352 + 5120];  // ~68 KB
    __shared__ int said[32];
    float* sF  = smem;            // [32][386]
    float* sH1 = smem + 12352;    // [32][160]
    float* sH2 = smem;            // [32][128]
    float* sH3 = smem + 4096;     // [32][96]
    const int t = threadIdx.x;

    if (t < 32) said[t] = (t < nA) ? bidx[offs[e] + start + t] : -1;
    __syncthreads();

    for (int i = t; i < 32 * 386; i += 256) {
        int a = i / 386, k = i - a * 386;
        int atom = said[a];
        float v = 0.0f;
        if (atom >= 0)
            v = (k < 384) ? aev[(long)atom * 384 + k]
                          : (k == 384 ? qv[atom] : esp[atom]);
        sF[i] = v;
    }
    __syncthreads();
    dense_tile<386, 160, true>(sF,  W1 + e * 386 * 160, b1 + e * 160, sH1, t);
    __syncthreads();
    dense_tile<160, 128, true>(sH1, W2 + e * 160 * 128, b2 + e * 128, sH2, t);
    __syncthreads();
    dense_tile<128,  96, true>(sH2, W3 + e * 128 * 96,  b3 + e * 96,  sH3, t);
    __syncthreads();
    if (t < nA) {
        float acc = 0.0f;
        const float* w4 = W4 + e * 96;
#pragma unroll
        for (int u = 0; u < 96; ++u) acc = fmaf(sH3[t * 96 + u], w4[u], acc);
        outat[said[t]] = acc + b4[e];
    }
}

// ---------------- Phase 5: per-molecule energy -----------------------------
__global__ __launch_bounds__(64) void energy_kernel(
    const float* __restrict__ outat, const float* __restrict__ coul,
    float* __restrict__ o_energy)
{
    int m = blockIdx.x, t = threadIdx.x;
    float v = outat[m * 64 + t];
#pragma unroll
    for (int o = 32; o > 0; o >>= 1) v += __shfl_xor(v, o);
    if (t == 0) o_energy[m] = v + coul[m];
}

extern "C" void kernel_launch(void* const* d_in, const int* in_sizes, int n_in,
                              void* d_out, int out_size, void* d_ws, size_t ws_size,
                              hipStream_t stream)
{
    const int*   species = (const int*)  d_in[0];
    const float* coords  = (const float*)d_in[1];
    const float* netq    = (const float*)d_in[2];
    const float* aev     = (const float*)d_in[3];
    const float* cW1 = (const float*)d_in[4];
    const float* cb1 = (const float*)d_in[5];
    const float* cW2 = (const float*)d_in[6];
    const float* cb2 = (const float*)d_in[7];
    const float* cW3 = (const float*)d_in[8];
    const float* cb3 = (const float*)d_in[9];
    const float* cW4 = (const float*)d_in[10];
    const float* cb4 = (const float*)d_in[11];
    const float* W1  = (const float*)d_in[12];
    const float* b1  = (const float*)d_in[13];
    const float* W2  = (const float*)d_in[14];
    const float* b2  = (const float*)d_in[15];
    const float* W3  = (const float*)d_in[16];
    const float* b3  = (const float*)d_in[17];
    const float* W4  = (const float*)d_in[18];
    const float* b4  = (const float*)d_in[19];

    const int N = in_sizes[2];          // 512
    const int n = in_sizes[0] / N;      // 64
    const int A = N * n;                // 32768

    // workspace layout (floats unless noted): chi | q | esp | out_atom | coulomb | ints
    float* ws      = (float*)d_ws;
    float* chi     = ws;
    float* qv      = ws + (size_t)A;
    float* esp     = ws + (size_t)2 * A;
    float* outat   = ws + (size_t)3 * A;
    float* coul    = ws + (size_t)4 * A;
    int*   counts  = (int*)(coul + N);
    int*   offs    = counts + 8;
    int*   cursors = offs + 9;
    int*   bidx    = cursors + 8;

    float* o_species = (float*)d_out;        // A elems (species as float)
    float* o_energy  = o_species + A;        // N elems
    float* o_q       = o_energy + N;         // A elems

    chi_kernel<<<A / 32, 256, 0, stream>>>(aev, species, cW1, cb1, cW2, cb2,
                                           cW3, cb3, cW4, cb4, chi);
    mol_kernel<<<N, 64, 0, stream>>>(species, coords, netq, chi, qv, esp, coul,
                                     o_species, o_q);
    init_kernel<<<1, 64, 0, stream>>>(counts, cursors);
    count_kernel<<<(A + 255) / 256, 256, 0, stream>>>(species, counts, outat, A);
    scan_kernel<<<1, 1, 0, stream>>>(counts, offs);
    fill_kernel<<<(A + 255) / 256, 256, 0, stream>>>(species, offs, cursors, bidx, A);
    int tilesMax = (A + 31) / 32;
    expert_kernel<<<8 * tilesMax, 256, 0, stream>>>(aev, qv, esp, W1, b1, W2, b2,
                                                    W3, b3, W4, b4, counts, offs,
                                                    bidx, outat, tilesMax);
    energy_kernel<<<N, 64, 0, stream>>>(outat, coul, o_energy);
}

// Round 2
// 442.620 us; speedup vs baseline: 2.9139x; 2.9139x over previous
//
#include <hip/hip_runtime.h>
#include <math.h>

#define A0_INV (1.0f/0.529177249f)

typedef __bf16 bf16x8 __attribute__((ext_vector_type(8)));
typedef __bf16 bf16x4 __attribute__((ext_vector_type(4)));
typedef float  f32x4  __attribute__((ext_vector_type(4)));

__device__ __constant__ float c_SIGMA[8] = {
    0.5515909f, 1.8886297f, 1.3225029f, 1.2316629f,
    2.1884933f, 1.7750372f, 1.3677907f, 1.3820058f};

__device__ __forceinline__ float celu01(float x) {
    return x > 0.0f ? x : 0.1f * expm1f(x * 10.0f);
}
__device__ __forceinline__ float softplusf_(float x) {
    return fmaxf(x, 0.0f) + log1pf(expf(-fabsf(x)));
}

// ---- pack weights (K,OUT) f32 -> B-fragment order bf16: Bp[e][nt][kt][lane][8]
// fragment: lane l holds B[k][col], col = nt*16 + (l&15), k = kt*32 + (l>>4)*8 + j
__global__ void pack_b_kernel(const float* __restrict__ W, __bf16* __restrict__ Bp,
                              int K, int OUT, int NT, int KT, int total)
{
    int idx = blockIdx.x * 256 + threadIdx.x;
    if (idx >= total) return;
    int lane = idx & 63;
    int rest = idx >> 6;
    int kt = rest % KT; rest /= KT;
    int nt = rest % NT;
    int e  = rest / NT;
    int col = nt * 16 + (lane & 15);
    int k0  = kt * 32 + (lane >> 4) * 8;
    bf16x8 o;
#pragma unroll
    for (int j = 0; j < 8; ++j) {
        int k = k0 + j;
        float v = (k < K) ? W[((long)e * K + k) * OUT + col] : 0.0f;
        o[j] = (__bf16)v;
    }
    *((bf16x8*)Bp + idx) = o;
}

// ---- one MFMA MLP layer over a 64-atom LDS tile ----
// A: sIn [64][INS] bf16 row-major (atoms x features). B: packed fragments.
// 4 waves: wave w computes N-tiles {w, w+4, ...}; each wave all 4 M-tiles.
// C/D layout (m89-verified): col = lane&15, row = (lane>>4)*4 + r.
template<int NT, int KT, int INS, int OUTS, bool CELU>
__device__ __forceinline__ void mlp_layer(const __bf16* sIn, const bf16x8* __restrict__ Bp,
                                          const float* __restrict__ bias, __bf16* sOut, int tid)
{
    const int lane = tid & 63;
    const int wid  = tid >> 6;
    const int r16  = lane & 15;
    const int g    = lane >> 4;
    constexpr int NJ = (NT + 3) / 4;
    f32x4 acc[4][NJ];
#pragma unroll
    for (int mt = 0; mt < 4; ++mt)
#pragma unroll
        for (int j = 0; j < NJ; ++j)
            acc[mt][j] = (f32x4){0.f, 0.f, 0.f, 0.f};

    for (int kt = 0; kt < KT; ++kt) {
        bf16x8 a[4];
#pragma unroll
        for (int mt = 0; mt < 4; ++mt)
            a[mt] = *(const bf16x8*)(sIn + (mt * 16 + r16) * INS + kt * 32 + g * 8);
#pragma unroll
        for (int j = 0; j < NJ; ++j) {
            const int nt = wid + 4 * j;
            if (nt < NT) {
                bf16x8 b = Bp[(nt * KT + kt) * 64 + lane];
#pragma unroll
                for (int mt = 0; mt < 4; ++mt)
                    acc[mt][j] = __builtin_amdgcn_mfma_f32_16x16x32_bf16(a[mt], b, acc[mt][j], 0, 0, 0);
            }
        }
    }
#pragma unroll
    for (int j = 0; j < NJ; ++j) {
        const int nt = wid + 4 * j;
        if (nt < NT) {
            const float bb = bias[nt * 16 + r16];
#pragma unroll
            for (int mt = 0; mt < 4; ++mt)
#pragma unroll
                for (int r = 0; r < 4; ++r) {
                    float v = acc[mt][j][r] + bb;
                    if (CELU) v = celu01(v);
                    sOut[(mt * 16 + g * 4 + r) * OUTS + nt * 16 + r16] = (__bf16)v;
                }
        }
    }
}

// ---------------- chi MLP: 64 atoms / block, MFMA ----------------
__global__ __launch_bounds__(256) void chi_mfma_kernel(
    const float* __restrict__ aev, const int* __restrict__ species,
    const __bf16* __restrict__ bp1, const __bf16* __restrict__ bp2, const __bf16* __restrict__ bp3,
    const float* __restrict__ b1, const float* __restrict__ b2, const float* __restrict__ b3,
    const float* __restrict__ W4, const float* __restrict__ b4,
    float* __restrict__ chi_out)
{
    __shared__ __align__(16) unsigned char smem[51200 + 22528];   // 73.7 KB
    __bf16* sFeat = (__bf16*)smem;              // [64][400] (384 used)
    __bf16* sAct1 = (__bf16*)(smem + 51200);    // [64][176] (160 used)
    __bf16* sAct2 = (__bf16*)smem;              // [64][144] (alias dead sFeat)
    __bf16* sAct3 = (__bf16*)(smem + 18432);    // [64][112]
    const int t = threadIdx.x;
    const long base = (long)blockIdx.x * 64;

    for (int i = t; i < 64 * 96; i += 256) {
        int row = i / 96, c4 = (i - row * 96) * 4;
        float4 v = *(const float4*)(aev + (base + row) * 384 + c4);
        bf16x4 o = {(__bf16)v.x, (__bf16)v.y, (__bf16)v.z, (__bf16)v.w};
        *(bf16x4*)(sFeat + row * 400 + c4) = o;
    }
    __syncthreads();
    mlp_layer<10, 12, 400, 176, true>(sFeat, (const bf16x8*)bp1, b1, sAct1, t);
    __syncthreads();
    mlp_layer<8, 5, 176, 144, true>(sAct1, (const bf16x8*)bp2, b2, sAct2, t);
    __syncthreads();
    mlp_layer<6, 4, 144, 112, true>(sAct2, (const bf16x8*)bp3, b3, sAct3, t);
    __syncthreads();
    if (t < 64) {
        const __bf16* h = sAct3 + t * 112;
        float acc = 0.f;
#pragma unroll 8
        for (int u = 0; u < 96; ++u) acc = fmaf((float)h[u], W4[u], acc);
        float chiv = softplusf_(acc + b4[0]);
        long atom = base + t;
        if (species[atom] == -1) chiv = 0.f;
        chi_out[atom] = chiv;
    }
}

// ---------------- per-molecule q / ESP / coulomb (256 threads) -------------
__global__ __launch_bounds__(256) void mol_kernel(
    const int* __restrict__ species, const float* __restrict__ coords,
    const float* __restrict__ netq, const float* __restrict__ chi,
    float* __restrict__ qv, float* __restrict__ esp, float* __restrict__ coul,
    float* __restrict__ o_species, float* __restrict__ o_q)
{
    const int m = blockIdx.x, t = threadIdx.x;
    const int j = t & 63, q4 = t >> 6;
    const int atom = m * 64 + j;
    __shared__ float sx[64], sy[64], sz[64], sq[64], ss2[64];
    __shared__ float sEsp[4][64];

    int s = species[atom];
    float pad = (s != -1) ? 1.0f : 0.0f;
    float chij = chi[atom];

    float cs = chij, na = pad;        // each wave spans all 64 atoms
#pragma unroll
    for (int o = 32; o > 0; o >>= 1) {
        cs += __shfl_xor(cs, o);
        na += __shfl_xor(na, o);
    }
    float qc = netq[m];
    float k_net = 1.0f + fabsf(qc) / cs;
    float chi_mean = cs / na;
    float k_p = (qc > 0.0f) ? k_net : 1.0f;
    float k_n = (qc < 0.0f) ? k_net : 1.0f;
    float qj = (-k_n * chij + k_p * chi_mean) * pad;

    float sg = c_SIGMA[s < 0 ? 0 : s];
    float x = coords[atom * 3 + 0], y = coords[atom * 3 + 1], z = coords[atom * 3 + 2];
    if (q4 == 0) { sx[j] = x; sy[j] = y; sz[j] = z; sq[j] = qj; ss2[j] = sg * sg; }
    __syncthreads();

    float s2j = sg * sg;
    float ej = 0.0f;
#pragma unroll
    for (int k = 0; k < 16; ++k) {
        int i = q4 * 16 + k;
        if (i == j) continue;
        float dx = sx[i] - x, dy = sy[i] - y, dz = sz[i] - z;
        float d = sqrtf(dx * dx + dy * dy + dz * dz + 1e-16f) * A0_INV;
        float ssum = fmaxf(ss2[i] + s2j, 1e-8f);
        float jij = erff(d * rsqrtf(2.0f * ssum)) / d;
        ej = fmaf(sq[i], jij, ej);
    }
    sEsp[q4][j] = ej;
    __syncthreads();
    if (q4 == 0) {
        float e = (sEsp[0][j] + sEsp[1][j]) + (sEsp[2][j] + sEsp[3][j]);
        e *= pad;
        float ce = qj * e;
#pragma unroll
        for (int o = 32; o > 0; o >>= 1) ce += __shfl_xor(ce, o);
        if (j == 0) coul[m] = 0.5f * ce;
        qv[atom] = qj;
        esp[atom] = e;
        o_species[atom] = (float)s;
        o_q[atom] = qj;
    }
}

// ---------------- species bucketing -------------------------------
__global__ void init_kernel(int* counts, int* cursors) {
    int t = threadIdx.x;
    if (t < 8) { counts[t] = 0; cursors[t] = 0; }
}
__global__ void count_kernel(const int* __restrict__ species, int* counts,
                             float* __restrict__ outat, int A) {
    int a = blockIdx.x * 256 + threadIdx.x;
    if (a < A) {
        outat[a] = 0.0f;
        int s = species[a];
        if (s >= 0) atomicAdd(&counts[s], 1);
    }
}
__global__ void scan_kernel(const int* counts, int* offs) {
    offs[0] = 0;
    for (int e = 0; e < 8; ++e) offs[e + 1] = offs[e] + counts[e];
}
__global__ void fill_kernel(const int* __restrict__ species, const int* offs,
                            int* cursors, int* bidx, int A) {
    int a = blockIdx.x * 256 + threadIdx.x;
    if (a < A) {
        int s = species[a];
        if (s >= 0) {
            int pos = offs[s] + atomicAdd(&cursors[s], 1);
            bidx[pos] = a;
        }
    }
}

// ---------------- routed expert MLP: 64 atoms / block, MFMA ----------------
__global__ __launch_bounds__(256) void expert_mfma_kernel(
    const float* __restrict__ aev, const float* __restrict__ qv, const float* __restrict__ esp,
    const __bf16* __restrict__ bp1, const __bf16* __restrict__ bp2, const __bf16* __restrict__ bp3,
    const float* __restrict__ b1, const float* __restrict__ b2, const float* __restrict__ b3,
    const float* __restrict__ W4, const float* __restrict__ b4,
    const int* __restrict__ counts, const int* __restrict__ offs, const int* __restrict__ bidx,
    float* __restrict__ outat, int tilesMax)
{
    const int e = blockIdx.x / tilesMax;
    const int tile = blockIdx.x - e * tilesMax;
    const int cnt = counts[e];
    const int start = tile * 64;
    if (start >= cnt) return;

    __shared__ __align__(16) unsigned char smem[55296 + 22528];   // 76 KB
    __shared__ int said[64];
    __bf16* sFeat = (__bf16*)smem;            // [64][432] (416 used: 384 aev | q | esp | 0-pad)
    __bf16* sAct1 = (__bf16*)(smem + 55296);  // [64][176]
    __bf16* sAct2 = (__bf16*)smem;            // [64][144] (alias dead sFeat)
    __bf16* sAct3 = (__bf16*)(smem + 18432);  // [64][112]
    const int t = threadIdx.x;

    if (t < 64) said[t] = (start + t < cnt) ? bidx[offs[e] + start + t] : -1;
    __syncthreads();

    for (int i = t; i < 64 * 104; i += 256) {
        int row = i / 104, c4 = (i - row * 104) * 4;
        int atom = said[row];
        bf16x4 o;
        if (atom >= 0 && c4 < 384) {
            float4 v = *(const float4*)(aev + (long)atom * 384 + c4);
            o[0] = (__bf16)v.x; o[1] = (__bf16)v.y; o[2] = (__bf16)v.z; o[3] = (__bf16)v.w;
        } else {
            float a0 = 0.f, a1 = 0.f;
            if (atom >= 0 && c4 == 384) { a0 = qv[atom]; a1 = esp[atom]; }
            o[0] = (__bf16)a0; o[1] = (__bf16)a1; o[2] = (__bf16)0.f; o[3] = (__bf16)0.f;
        }
        *(bf16x4*)(sFeat + row * 432 + c4) = o;
    }
    __syncthreads();
    mlp_layer<10, 13, 432, 176, true>(sFeat, (const bf16x8*)bp1 + (size_t)e * 10 * 13 * 64,
                                      b1 + e * 160, sAct1, t);
    __syncthreads();
    mlp_layer<8, 5, 176, 144, true>(sAct1, (const bf16x8*)bp2 + (size_t)e * 8 * 5 * 64,
                                    b2 + e * 128, sAct2, t);
    __syncthreads();
    mlp_layer<6, 4, 144, 112, true>(sAct2, (const bf16x8*)bp3 + (size_t)e * 6 * 4 * 64,
                                    b3 + e * 96, sAct3, t);
    __syncthreads();
    if (t < 64) {
        int atom = said[t];
        if (atom >= 0) {
            const __bf16* h = sAct3 + t * 112;
            const float* w4 = W4 + e * 96;
            float acc = 0.f;
#pragma unroll 8
            for (int u = 0; u < 96; ++u) acc = fmaf((float)h[u], w4[u], acc);
            outat[atom] = acc + b4[e];
        }
    }
}

// ---------------- per-molecule energy -----------------------------
__global__ __launch_bounds__(64) void energy_kernel(
    const float* __restrict__ outat, const float* __restrict__ coul,
    float* __restrict__ o_energy)
{
    int m = blockIdx.x, t = threadIdx.x;
    float v = outat[m * 64 + t];
#pragma unroll
    for (int o = 32; o > 0; o >>= 1) v += __shfl_xor(v, o);
    if (t == 0) o_energy[m] = v + coul[m];
}

extern "C" void kernel_launch(void* const* d_in, const int* in_sizes, int n_in,
                              void* d_out, int out_size, void* d_ws, size_t ws_size,
                              hipStream_t stream)
{
    const int*   species = (const int*)  d_in[0];
    const float* coords  = (const float*)d_in[1];
    const float* netq    = (const float*)d_in[2];
    const float* aev     = (const float*)d_in[3];
    const float* cW1 = (const float*)d_in[4];
    const float* cb1 = (const float*)d_in[5];
    const float* cW2 = (const float*)d_in[6];
    const float* cb2 = (const float*)d_in[7];
    const float* cW3 = (const float*)d_in[8];
    const float* cb3 = (const float*)d_in[9];
    const float* cW4 = (const float*)d_in[10];
    const float* cb4 = (const float*)d_in[11];
    const float* W1  = (const float*)d_in[12];
    const float* b1  = (const float*)d_in[13];
    const float* W2  = (const float*)d_in[14];
    const float* b2  = (const float*)d_in[15];
    const float* W3  = (const float*)d_in[16];
    const float* b3  = (const float*)d_in[17];
    const float* W4  = (const float*)d_in[18];
    const float* b4  = (const float*)d_in[19];

    const int N = in_sizes[2];          // 512
    const int n = in_sizes[0] / N;      // 64
    const int A = N * n;                // 32768

    // ---- workspace layout ----
    float* fbase   = (float*)d_ws;
    float* chi     = fbase;
    float* qv      = fbase + (size_t)A;
    float* esp     = fbase + (size_t)2 * A;
    float* outat   = fbase + (size_t)3 * A;
    float* coul    = fbase + (size_t)4 * A;
    int*   counts  = (int*)(coul + N);
    int*   offs    = counts + 8;
    int*   cursors = offs + 9;
    int*   bidx    = cursors + 8;
    uintptr_t p = ((uintptr_t)(bidx + A) + 15) & ~(uintptr_t)15;
    __bf16* bp_c1 = (__bf16*)p; p += (size_t)10 * 12 * 512 * 2;        // 61440 bf16
    __bf16* bp_c2 = (__bf16*)p; p += (size_t)8  * 5  * 512 * 2;
    __bf16* bp_c3 = (__bf16*)p; p += (size_t)6  * 4  * 512 * 2;
    __bf16* bp_e1 = (__bf16*)p; p += (size_t)8 * 10 * 13 * 512 * 2;
    __bf16* bp_e2 = (__bf16*)p; p += (size_t)8 * 8  * 5  * 512 * 2;
    __bf16* bp_e3 = (__bf16*)p; p += (size_t)8 * 6  * 4  * 512 * 2;

    float* o_species = (float*)d_out;        // A elems (species as float)
    float* o_energy  = o_species + A;        // N elems
    float* o_q       = o_energy + N;         // A elems

    // ---- pack weights to fragment order (bf16) ----
    pack_b_kernel<<<(7680  + 255) / 256, 256, 0, stream>>>(cW1, bp_c1, 384, 160, 10, 12, 7680);
    pack_b_kernel<<<(2560  + 255) / 256, 256, 0, stream>>>(cW2, bp_c2, 160, 128, 8, 5, 2560);
    pack_b_kernel<<<(1536  + 255) / 256, 256, 0, stream>>>(cW3, bp_c3, 128, 96, 6, 4, 1536);
    pack_b_kernel<<<(66560 + 255) / 256, 256, 0, stream>>>(W1,  bp_e1, 386, 160, 10, 13, 66560);
    pack_b_kernel<<<(20480 + 255) / 256, 256, 0, stream>>>(W2,  bp_e2, 160, 128, 8, 5, 20480);
    pack_b_kernel<<<(12288 + 255) / 256, 256, 0, stream>>>(W3,  bp_e3, 128, 96, 6, 4, 12288);

    chi_mfma_kernel<<<A / 64, 256, 0, stream>>>(aev, species, bp_c1, bp_c2, bp_c3,
                                                cb1, cb2, cb3, cW4, cb4, chi);
    mol_kernel<<<N, 256, 0, stream>>>(species, coords, netq, chi, qv, esp, coul,
                                      (float*)d_out, o_q);
    init_kernel<<<1, 64, 0, stream>>>(counts, cursors);
    count_kernel<<<(A + 255) / 256, 256, 0, stream>>>(species, counts, outat, A);
    scan_kernel<<<1, 1, 0, stream>>>(counts, offs);
    fill_kernel<<<(A + 255) / 256, 256, 0, stream>>>(species, offs, cursors, bidx, A);
    int tilesMax = (A + 63) / 64;
    expert_mfma_kernel<<<8 * tilesMax, 256, 0, stream>>>(aev, qv, esp, bp_e1, bp_e2, bp_e3,
                                                         b1, b2, b3, W4, b4,
                                                         counts, offs, bidx, outat, tilesMax);
    energy_kernel<<<N, 64, 0, stream>>>(outat, coul, o_energy);
}

// Round 3
// 177.327 us; speedup vs baseline: 7.2733x; 2.4961x over previous
//
#include <hip/hip_runtime.h>
#include <math.h>

#define A0_INV (1.0f/0.529177249f)

typedef __bf16 bf16x8 __attribute__((ext_vector_type(8)));
typedef __bf16 bf16x4 __attribute__((ext_vector_type(4)));
typedef float  f32x4  __attribute__((ext_vector_type(4)));

__device__ __constant__ float c_SIGMA[8] = {
    0.5515909f, 1.8886297f, 1.3225029f, 1.2316629f,
    2.1884933f, 1.7750372f, 1.3677907f, 1.3820058f};

__device__ __forceinline__ float celu01(float x) {
    return x > 0.0f ? x : 0.1f * expm1f(x * 10.0f);
}
__device__ __forceinline__ float softplusf_(float x) {
    return fmaxf(x, 0.0f) + log1pf(expf(-fabsf(x)));
}

// ---- pack weights (K,OUT) f32 -> B-fragment order bf16: Bp[e][nt][kt][lane][8]
// fragment: lane l holds B[k][col], col = nt*16 + (l&15), k = kt*32 + (l>>4)*8 + j
__device__ __forceinline__ void pack_one(int idx, const float* __restrict__ W,
                                         __bf16* __restrict__ Bp,
                                         int K, int OUT, int NT, int KT)
{
    int lane = idx & 63;
    int rest = idx >> 6;
    int kt = rest % KT; rest /= KT;
    int nt = rest % NT;
    int e  = rest / NT;
    int col = nt * 16 + (lane & 15);
    int k0  = kt * 32 + (lane >> 4) * 8;
    bf16x8 o;
#pragma unroll
    for (int j = 0; j < 8; ++j) {
        int k = k0 + j;
        float v = (k < K) ? W[((long)e * K + k) * OUT + col] : 0.0f;
        o[j] = (__bf16)v;
    }
    *((bf16x8*)Bp + idx) = o;
}

// segment boundaries (fragment counts): c1 7680 | c2 2560 | c3 1536 | e1 66560 | e2 20480 | e3 12288
__global__ __launch_bounds__(256) void pack_all_kernel(
    const float* __restrict__ cW1, const float* __restrict__ cW2, const float* __restrict__ cW3,
    const float* __restrict__ W1,  const float* __restrict__ W2,  const float* __restrict__ W3,
    __bf16* bp_c1, __bf16* bp_c2, __bf16* bp_c3,
    __bf16* bp_e1, __bf16* bp_e2, __bf16* bp_e3)
{
    int idx = blockIdx.x * 256 + threadIdx.x;
    if      (idx <   7680) pack_one(idx,          cW1, bp_c1, 384, 160, 10, 12);
    else if (idx <  10240) pack_one(idx - 7680,   cW2, bp_c2, 160, 128,  8,  5);
    else if (idx <  11776) pack_one(idx - 10240,  cW3, bp_c3, 128,  96,  6,  4);
    else if (idx <  78336) pack_one(idx - 11776,  W1,  bp_e1, 386, 160, 10, 13);
    else if (idx <  98816) pack_one(idx - 78336,  W2,  bp_e2, 160, 128,  8,  5);
    else if (idx < 111104) pack_one(idx - 98816,  W3,  bp_e3, 128,  96,  6,  4);
}

// ---- one MFMA MLP layer over a 64-atom LDS tile ----
template<int NT, int KT, int INS, int OUTS, bool CELU>
__device__ __forceinline__ void mlp_layer(const __bf16* sIn, const bf16x8* __restrict__ Bp,
                                          const float* __restrict__ bias, __bf16* sOut, int tid)
{
    const int lane = tid & 63;
    const int wid  = tid >> 6;
    const int r16  = lane & 15;
    const int g    = lane >> 4;
    constexpr int NJ = (NT + 3) / 4;
    f32x4 acc[4][NJ];
#pragma unroll
    for (int mt = 0; mt < 4; ++mt)
#pragma unroll
        for (int j = 0; j < NJ; ++j)
            acc[mt][j] = (f32x4){0.f, 0.f, 0.f, 0.f};

    for (int kt = 0; kt < KT; ++kt) {
        bf16x8 a[4];
#pragma unroll
        for (int mt = 0; mt < 4; ++mt)
            a[mt] = *(const bf16x8*)(sIn + (mt * 16 + r16) * INS + kt * 32 + g * 8);
#pragma unroll
        for (int j = 0; j < NJ; ++j) {
            const int nt = wid + 4 * j;
            if (nt < NT) {
                bf16x8 b = Bp[(nt * KT + kt) * 64 + lane];
#pragma unroll
                for (int mt = 0; mt < 4; ++mt)
                    acc[mt][j] = __builtin_amdgcn_mfma_f32_16x16x32_bf16(a[mt], b, acc[mt][j], 0, 0, 0);
            }
        }
    }
#pragma unroll
    for (int j = 0; j < NJ; ++j) {
        const int nt = wid + 4 * j;
        if (nt < NT) {
            const float bb = bias[nt * 16 + r16];
#pragma unroll
            for (int mt = 0; mt < 4; ++mt)
#pragma unroll
                for (int r = 0; r < 4; ++r) {
                    float v = acc[mt][j][r] + bb;
                    if (CELU) v = celu01(v);
                    sOut[(mt * 16 + g * 4 + r) * OUTS + nt * 16 + r16] = (__bf16)v;
                }
        }
    }
}

// ---------------- chi MLP: 64 atoms / block, MFMA ----------------
__global__ __launch_bounds__(256) void chi_mfma_kernel(
    const float* __restrict__ aev, const int* __restrict__ species,
    const __bf16* __restrict__ bp1, const __bf16* __restrict__ bp2, const __bf16* __restrict__ bp3,
    const float* __restrict__ b1, const float* __restrict__ b2, const float* __restrict__ b3,
    const float* __restrict__ W4, const float* __restrict__ b4,
    float* __restrict__ chi_out)
{
    __shared__ __align__(16) unsigned char smem[51200 + 22528];   // 73.7 KB
    __bf16* sFeat = (__bf16*)smem;              // [64][400] (384 used)
    __bf16* sAct1 = (__bf16*)(smem + 51200);    // [64][176] (160 used)
    __bf16* sAct2 = (__bf16*)smem;              // [64][144] (alias dead sFeat)
    __bf16* sAct3 = (__bf16*)(smem + 18432);    // [64][112]
    const int t = threadIdx.x;
    const long base = (long)blockIdx.x * 64;

    for (int i = t; i < 64 * 96; i += 256) {
        int row = i / 96, c4 = (i - row * 96) * 4;
        float4 v = *(const float4*)(aev + (base + row) * 384 + c4);
        bf16x4 o = {(__bf16)v.x, (__bf16)v.y, (__bf16)v.z, (__bf16)v.w};
        *(bf16x4*)(sFeat + row * 400 + c4) = o;
    }
    __syncthreads();
    mlp_layer<10, 12, 400, 176, true>(sFeat, (const bf16x8*)bp1, b1, sAct1, t);
    __syncthreads();
    mlp_layer<8, 5, 176, 144, true>(sAct1, (const bf16x8*)bp2, b2, sAct2, t);
    __syncthreads();
    mlp_layer<6, 4, 144, 112, true>(sAct2, (const bf16x8*)bp3, b3, sAct3, t);
    __syncthreads();
    if (t < 64) {
        const __bf16* h = sAct3 + t * 112;
        float acc = 0.f;
#pragma unroll 8
        for (int u = 0; u < 96; ++u) acc = fmaf((float)h[u], W4[u], acc);
        float chiv = softplusf_(acc + b4[0]);
        long atom = base + t;
        if (species[atom] == -1) chiv = 0.f;
        chi_out[atom] = chiv;
    }
}

// ---------------- per-molecule q / ESP / coulomb (256 threads) -------------
__global__ __launch_bounds__(256) void mol_kernel(
    const int* __restrict__ species, const float* __restrict__ coords,
    const float* __restrict__ netq, const float* __restrict__ chi,
    float* __restrict__ qv, float* __restrict__ esp, float* __restrict__ coul,
    float* __restrict__ o_species, float* __restrict__ o_q)
{
    const int m = blockIdx.x, t = threadIdx.x;
    const int j = t & 63, q4 = t >> 6;
    const int atom = m * 64 + j;
    __shared__ float sx[64], sy[64], sz[64], sq[64], ss2[64];
    __shared__ float sEsp[4][64];

    int s = species[atom];
    float pad = (s != -1) ? 1.0f : 0.0f;
    float chij = chi[atom];

    float cs = chij, na = pad;        // each wave spans all 64 atoms
#pragma unroll
    for (int o = 32; o > 0; o >>= 1) {
        cs += __shfl_xor(cs, o);
        na += __shfl_xor(na, o);
    }
    float qc = netq[m];
    float k_net = 1.0f + fabsf(qc) / cs;
    float chi_mean = cs / na;
    float k_p = (qc > 0.0f) ? k_net : 1.0f;
    float k_n = (qc < 0.0f) ? k_net : 1.0f;
    float qj = (-k_n * chij + k_p * chi_mean) * pad;

    float sg = c_SIGMA[s < 0 ? 0 : s];
    float x = coords[atom * 3 + 0], y = coords[atom * 3 + 1], z = coords[atom * 3 + 2];
    if (q4 == 0) { sx[j] = x; sy[j] = y; sz[j] = z; sq[j] = qj; ss2[j] = sg * sg; }
    __syncthreads();

    float s2j = sg * sg;
    float ej = 0.0f;
#pragma unroll
    for (int k = 0; k < 16; ++k) {
        int i = q4 * 16 + k;
        if (i == j) continue;
        float dx = sx[i] - x, dy = sy[i] - y, dz = sz[i] - z;
        float d = sqrtf(dx * dx + dy * dy + dz * dz + 1e-16f) * A0_INV;
        float ssum = fmaxf(ss2[i] + s2j, 1e-8f);
        float jij = erff(d * rsqrtf(2.0f * ssum)) / d;
        ej = fmaf(sq[i], jij, ej);
    }
    sEsp[q4][j] = ej;
    __syncthreads();
    if (q4 == 0) {
        float e = (sEsp[0][j] + sEsp[1][j]) + (sEsp[2][j] + sEsp[3][j]);
        e *= pad;
        float ce = qj * e;
#pragma unroll
        for (int o = 32; o > 0; o >>= 1) ce += __shfl_xor(ce, o);
        if (j == 0) coul[m] = 0.5f * ce;
        qv[atom] = qj;
        esp[atom] = e;
        o_species[atom] = (float)s;
        o_q[atom] = qj;
    }
}

// ---------------- species bucketing: deterministic, zero global atomics ----
__global__ __launch_bounds__(256) void bucket_count_kernel(
    const int* __restrict__ species, int* __restrict__ blockCounts,
    float* __restrict__ outat, int A)
{
    __shared__ int hist[8];
    const int t = threadIdx.x;
    if (t < 8) hist[t] = 0;
    __syncthreads();
    int a = blockIdx.x * 256 + t;
    if (a < A) {
        outat[a] = 0.0f;
        int s = species[a];
        if (s >= 0) atomicAdd(&hist[s], 1);   // LDS atomic, 8 bins, cheap
    }
    __syncthreads();
    if (t < 8) blockCounts[blockIdx.x * 8 + t] = hist[t];
}

__global__ void bucket_scan_kernel(int* __restrict__ blockCounts,
                                   int* __restrict__ counts, int* __restrict__ offs,
                                   int nBlocks)
{
    const int e = threadIdx.x;
    __shared__ int tot[8];
    if (e < 8) {
        int run = 0;
        for (int b = 0; b < nBlocks; ++b) {
            int c = blockCounts[b * 8 + e];
            blockCounts[b * 8 + e] = run;     // exclusive prefix within species
            run += c;
        }
        tot[e] = run;
    }
    __syncthreads();
    if (e == 0) {
        int o = 0;
        for (int i = 0; i < 8; ++i) { offs[i] = o; counts[i] = tot[i]; o += tot[i]; }
        offs[8] = o;
    }
}

__global__ __launch_bounds__(256) void bucket_fill_kernel(
    const int* __restrict__ species, const int* __restrict__ blockCounts,
    const int* __restrict__ offs, int* __restrict__ bidx, int A)
{
    __shared__ int waveCnt[4][8];
    const int t = threadIdx.x, lane = t & 63, w = t >> 6;
    int a = blockIdx.x * 256 + t;
    int s = (a < A) ? species[a] : -1;
    unsigned long long mymask = 0;
#pragma unroll
    for (int e = 0; e < 8; ++e) {
        unsigned long long b = __ballot(s == e);
        if (lane == e) waveCnt[w][e] = (int)__popcll(b);
        if (s == e) mymask = b;
    }
    __syncthreads();
    if (s >= 0) {
        int prefix = 0;
        for (int w2 = 0; w2 < w; ++w2) prefix += waveCnt[w2][s];
        int rank = (int)__popcll(mymask & ((1ull << lane) - 1ull));
        bidx[offs[s] + blockCounts[blockIdx.x * 8 + s] + prefix + rank] = a;
    }
}

// ---------------- routed expert MLP: 64 atoms / block, MFMA ----------------
__global__ __launch_bounds__(256) void expert_mfma_kernel(
    const float* __restrict__ aev, const float* __restrict__ qv, const float* __restrict__ esp,
    const __bf16* __restrict__ bp1, const __bf16* __restrict__ bp2, const __bf16* __restrict__ bp3,
    const float* __restrict__ b1, const float* __restrict__ b2, const float* __restrict__ b3,
    const float* __restrict__ W4, const float* __restrict__ b4,
    const int* __restrict__ counts, const int* __restrict__ offs, const int* __restrict__ bidx,
    float* __restrict__ outat, int tilesMax)
{
    const int e = blockIdx.x / tilesMax;
    const int tile = blockIdx.x - e * tilesMax;
    const int cnt = counts[e];
    const int start = tile * 64;
    if (start >= cnt) return;

    __shared__ __align__(16) unsigned char smem[55296 + 22528];   // 76 KB
    __shared__ int said[64];
    __bf16* sFeat = (__bf16*)smem;            // [64][432] (416 used: 384 aev | q | esp | 0-pad)
    __bf16* sAct1 = (__bf16*)(smem + 55296);  // [64][176]
    __bf16* sAct2 = (__bf16*)smem;            // [64][144] (alias dead sFeat)
    __bf16* sAct3 = (__bf16*)(smem + 18432);  // [64][112]
    const int t = threadIdx.x;

    if (t < 64) said[t] = (start + t < cnt) ? bidx[offs[e] + start + t] : -1;
    __syncthreads();

    for (int i = t; i < 64 * 104; i += 256) {
        int row = i / 104, c4 = (i - row * 104) * 4;
        int atom = said[row];
        bf16x4 o;
        if (atom >= 0 && c4 < 384) {
            float4 v = *(const float4*)(aev + (long)atom * 384 + c4);
            o[0] = (__bf16)v.x; o[1] = (__bf16)v.y; o[2] = (__bf16)v.z; o[3] = (__bf16)v.w;
        } else {
            float a0 = 0.f, a1 = 0.f;
            if (atom >= 0 && c4 == 384) { a0 = qv[atom]; a1 = esp[atom]; }
            o[0] = (__bf16)a0; o[1] = (__bf16)a1; o[2] = (__bf16)0.f; o[3] = (__bf16)0.f;
        }
        *(bf16x4*)(sFeat + row * 432 + c4) = o;
    }
    __syncthreads();
    mlp_layer<10, 13, 432, 176, true>(sFeat, (const bf16x8*)bp1 + (size_t)e * 10 * 13 * 64,
                                      b1 + e * 160, sAct1, t);
    __syncthreads();
    mlp_layer<8, 5, 176, 144, true>(sAct1, (const bf16x8*)bp2 + (size_t)e * 8 * 5 * 64,
                                    b2 + e * 128, sAct2, t);
    __syncthreads();
    mlp_layer<6, 4, 144, 112, true>(sAct2, (const bf16x8*)bp3 + (size_t)e * 6 * 4 * 64,
                                    b3 + e * 96, sAct3, t);
    __syncthreads();
    if (t < 64) {
        int atom = said[t];
        if (atom >= 0) {
            const __bf16* h = sAct3 + t * 112;
            const float* w4 = W4 + e * 96;
            float acc = 0.f;
#pragma unroll 8
            for (int u = 0; u < 96; ++u) acc = fmaf((float)h[u], w4[u], acc);
            outat[atom] = acc + b4[e];
        }
    }
}

// ---------------- per-molecule energy -----------------------------
__global__ __launch_bounds__(64) void energy_kernel(
    const float* __restrict__ outat, const float* __restrict__ coul,
    float* __restrict__ o_energy)
{
    int m = blockIdx.x, t = threadIdx.x;
    float v = outat[m * 64 + t];
#pragma unroll
    for (int o = 32; o > 0; o >>= 1) v += __shfl_xor(v, o);
    if (t == 0) o_energy[m] = v + coul[m];
}

extern "C" void kernel_launch(void* const* d_in, const int* in_sizes, int n_in,
                              void* d_out, int out_size, void* d_ws, size_t ws_size,
                              hipStream_t stream)
{
    const int*   species = (const int*)  d_in[0];
    const float* coords  = (const float*)d_in[1];
    const float* netq    = (const float*)d_in[2];
    const float* aev     = (const float*)d_in[3];
    const float* cW1 = (const float*)d_in[4];
    const float* cb1 = (const float*)d_in[5];
    const float* cW2 = (const float*)d_in[6];
    const float* cb2 = (const float*)d_in[7];
    const float* cW3 = (const float*)d_in[8];
    const float* cb3 = (const float*)d_in[9];
    const float* cW4 = (const float*)d_in[10];
    const float* cb4 = (const float*)d_in[11];
    const float* W1  = (const float*)d_in[12];
    const float* b1  = (const float*)d_in[13];
    const float* W2  = (const float*)d_in[14];
    const float* b2  = (const float*)d_in[15];
    const float* W3  = (const float*)d_in[16];
    const float* b3  = (const float*)d_in[17];
    const float* W4  = (const float*)d_in[18];
    const float* b4  = (const float*)d_in[19];

    const int N = in_sizes[2];          // 512
    const int n = in_sizes[0] / N;      // 64
    const int A = N * n;                // 32768
    const int nBlocks = (A + 255) / 256;

    // ---- workspace layout ----
    float* fbase   = (float*)d_ws;
    float* chi     = fbase;
    float* qv      = fbase + (size_t)A;
    float* esp     = fbase + (size_t)2 * A;
    float* outat   = fbase + (size_t)3 * A;
    float* coul    = fbase + (size_t)4 * A;
    int*   counts  = (int*)(coul + N);
    int*   offs    = counts + 8;
    int*   blockCounts = offs + 9;               // nBlocks*8 ints
    int*   bidx    = blockCounts + nBlocks * 8;
    uintptr_t p = ((uintptr_t)(bidx + A) + 15) & ~(uintptr_t)15;
    __bf16* bp_c1 = (__bf16*)p; p += (size_t)10 * 12 * 512 * 2;
    __bf16* bp_c2 = (__bf16*)p; p += (size_t)8  * 5  * 512 * 2;
    __bf16* bp_c3 = (__bf16*)p; p += (size_t)6  * 4  * 512 * 2;
    __bf16* bp_e1 = (__bf16*)p; p += (size_t)8 * 10 * 13 * 512 * 2;
    __bf16* bp_e2 = (__bf16*)p; p += (size_t)8 * 8  * 5  * 512 * 2;
    __bf16* bp_e3 = (__bf16*)p; p += (size_t)8 * 6  * 4  * 512 * 2;

    float* o_species = (float*)d_out;        // A elems (species as float)
    float* o_energy  = o_species + A;        // N elems
    float* o_q       = o_energy + N;         // A elems

    pack_all_kernel<<<(111104 + 255) / 256, 256, 0, stream>>>(
        cW1, cW2, cW3, W1, W2, W3, bp_c1, bp_c2, bp_c3, bp_e1, bp_e2, bp_e3);

    chi_mfma_kernel<<<A / 64, 256, 0, stream>>>(aev, species, bp_c1, bp_c2, bp_c3,
                                                cb1, cb2, cb3, cW4, cb4, chi);
    mol_kernel<<<N, 256, 0, stream>>>(species, coords, netq, chi, qv, esp, coul,
                                      (float*)d_out, o_q);
    bucket_count_kernel<<<nBlocks, 256, 0, stream>>>(species, blockCounts, outat, A);
    bucket_scan_kernel<<<1, 64, 0, stream>>>(blockCounts, counts, offs, nBlocks);
    bucket_fill_kernel<<<nBlocks, 256, 0, stream>>>(species, blockCounts, offs, bidx, A);
    int tilesMax = (A + 63) / 64;
    expert_mfma_kernel<<<8 * tilesMax, 256, 0, stream>>>(aev, qv, esp, bp_e1, bp_e2, bp_e3,
                                                         b1, b2, b3, W4, b4,
                                                         counts, offs, bidx, outat, tilesMax);
    energy_kernel<<<N, 64, 0, stream>>>(outat, coul, o_energy);
}

// Round 4
// 142.172 us; speedup vs baseline: 9.0718x; 1.2473x over previous
//
#include <hip/hip_runtime.h>
#include <math.h>

#define A0_INV (1.0f/0.529177249f)

typedef __bf16 bf16x8 __attribute__((ext_vector_type(8)));
typedef __bf16 bf16x4 __attribute__((ext_vector_type(4)));
typedef float  f32x4  __attribute__((ext_vector_type(4)));

__device__ __constant__ float c_SIGMA[8] = {
    0.5515909f, 1.8886297f, 1.3225029f, 1.2316629f,
    2.1884933f, 1.7750372f, 1.3677907f, 1.3820058f};

__device__ __forceinline__ float celu01(float x) {
    return x > 0.0f ? x : 0.1f * expm1f(x * 10.0f);
}
__device__ __forceinline__ float softplusf_(float x) {
    return fmaxf(x, 0.0f) + log1pf(expf(-fabsf(x)));
}

// ---- pack weights (K,OUT) f32 -> B-fragment order bf16: Bp[e][nt][kt][lane][8]
__device__ __forceinline__ void pack_one(int idx, const float* __restrict__ W,
                                         __bf16* __restrict__ Bp,
                                         int K, int OUT, int NT, int KT)
{
    int lane = idx & 63;
    int rest = idx >> 6;
    int kt = rest % KT; rest /= KT;
    int nt = rest % NT;
    int e  = rest / NT;
    int col = nt * 16 + (lane & 15);
    int k0  = kt * 32 + (lane >> 4) * 8;
    bf16x8 o;
#pragma unroll
    for (int j = 0; j < 8; ++j) {
        int k = k0 + j;
        float v = (k < K) ? W[((long)e * K + k) * OUT + col] : 0.0f;
        o[j] = (__bf16)v;
    }
    *((bf16x8*)Bp + idx) = o;
}

__global__ __launch_bounds__(256) void pack_all_kernel(
    const float* __restrict__ cW1, const float* __restrict__ cW2, const float* __restrict__ cW3,
    const float* __restrict__ W1,  const float* __restrict__ W2,  const float* __restrict__ W3,
    __bf16* bp_c1, __bf16* bp_c2, __bf16* bp_c3,
    __bf16* bp_e1, __bf16* bp_e2, __bf16* bp_e3)
{
    int idx = blockIdx.x * 256 + threadIdx.x;
    if      (idx <   7680) pack_one(idx,          cW1, bp_c1, 384, 160, 10, 12);
    else if (idx <  10240) pack_one(idx - 7680,   cW2, bp_c2, 160, 128,  8,  5);
    else if (idx <  11776) pack_one(idx - 10240,  cW3, bp_c3, 128,  96,  6,  4);
    else if (idx <  78336) pack_one(idx - 11776,  W1,  bp_e1, 386, 160, 10, 13);
    else if (idx <  98816) pack_one(idx - 78336,  W2,  bp_e2, 160, 128,  8,  5);
    else if (idx < 111104) pack_one(idx - 98816,  W3,  bp_e3, 128,  96,  6,  4);
}

// ---- one MFMA MLP layer over a 64-atom LDS tile, 1-deep B prefetch ----
template<int NT, int KT, int INS, int OUTS, bool CELU>
__device__ __forceinline__ void mlp_layer(const __bf16* sIn, const bf16x8* __restrict__ Bp,
                                          const float* __restrict__ bias, __bf16* sOut, int tid)
{
    const int lane = tid & 63;
    const int wid  = tid >> 6;
    const int r16  = lane & 15;
    const int g    = lane >> 4;
    constexpr int NJ = (NT + 3) / 4;
    f32x4 acc[4][NJ];
#pragma unroll
    for (int mt = 0; mt < 4; ++mt)
#pragma unroll
        for (int j = 0; j < NJ; ++j)
            acc[mt][j] = (f32x4){0.f, 0.f, 0.f, 0.f};

    bf16x8 bcur[NJ], bnxt[NJ];
#pragma unroll
    for (int j = 0; j < NJ; ++j) {
        const int nt = wid + 4 * j;
        if (nt < NT) bcur[j] = Bp[(nt * KT) * 64 + lane];
    }
    for (int kt = 0; kt < KT; ++kt) {
        bf16x8 a[4];
#pragma unroll
        for (int mt = 0; mt < 4; ++mt)
            a[mt] = *(const bf16x8*)(sIn + (mt * 16 + r16) * INS + kt * 32 + g * 8);
        if (kt + 1 < KT) {
#pragma unroll
            for (int j = 0; j < NJ; ++j) {
                const int nt = wid + 4 * j;
                if (nt < NT) bnxt[j] = Bp[(nt * KT + kt + 1) * 64 + lane];
            }
        }
#pragma unroll
        for (int j = 0; j < NJ; ++j) {
            const int nt = wid + 4 * j;
            if (nt < NT) {
#pragma unroll
                for (int mt = 0; mt < 4; ++mt)
                    acc[mt][j] = __builtin_amdgcn_mfma_f32_16x16x32_bf16(a[mt], bcur[j], acc[mt][j], 0, 0, 0);
            }
        }
#pragma unroll
        for (int j = 0; j < NJ; ++j) bcur[j] = bnxt[j];
    }
#pragma unroll
    for (int j = 0; j < NJ; ++j) {
        const int nt = wid + 4 * j;
        if (nt < NT) {
            const float bb = bias[nt * 16 + r16];
#pragma unroll
            for (int mt = 0; mt < 4; ++mt)
#pragma unroll
                for (int r = 0; r < 4; ++r) {
                    float v = acc[mt][j][r] + bb;
                    if (CELU) v = celu01(v);
                    sOut[(mt * 16 + g * 4 + r) * OUTS + nt * 16 + r16] = (__bf16)v;
                }
        }
    }
}

// vectorized final-layer dot: h[96] (bf16, 16B-aligned) . w4[96] (f32)
__device__ __forceinline__ float l4_dot(const __bf16* __restrict__ h,
                                        const float* __restrict__ w4)
{
    float acc = 0.f;
#pragma unroll
    for (int u8 = 0; u8 < 12; ++u8) {
        bf16x8 hv = *(const bf16x8*)(h + u8 * 8);
        float4 wa = *(const float4*)(w4 + u8 * 8);
        float4 wb = *(const float4*)(w4 + u8 * 8 + 4);
        acc = fmaf((float)hv[0], wa.x, acc);
        acc = fmaf((float)hv[1], wa.y, acc);
        acc = fmaf((float)hv[2], wa.z, acc);
        acc = fmaf((float)hv[3], wa.w, acc);
        acc = fmaf((float)hv[4], wb.x, acc);
        acc = fmaf((float)hv[5], wb.y, acc);
        acc = fmaf((float)hv[6], wb.z, acc);
        acc = fmaf((float)hv[7], wb.w, acc);
    }
    return acc;
}

// ---------------- chi MLP: 64 atoms / block, MFMA ----------------
__global__ __launch_bounds__(256) void chi_mfma_kernel(
    const float* __restrict__ aev, const int* __restrict__ species,
    const __bf16* __restrict__ bp1, const __bf16* __restrict__ bp2, const __bf16* __restrict__ bp3,
    const float* __restrict__ b1, const float* __restrict__ b2, const float* __restrict__ b3,
    const float* __restrict__ W4, const float* __restrict__ b4,
    float* __restrict__ chi_out)
{
    __shared__ __align__(16) unsigned char smem[51200 + 22528];   // 73.7 KB
    __bf16* sFeat = (__bf16*)smem;              // [64][400] (384 used)
    __bf16* sAct1 = (__bf16*)(smem + 51200);    // [64][176] (160 used)
    __bf16* sAct2 = (__bf16*)smem;              // [64][144] (alias dead sFeat)
    __bf16* sAct3 = (__bf16*)(smem + 18432);    // [64][112]
    const int t = threadIdx.x;
    const long base = (long)blockIdx.x * 64;

    for (int i = t; i < 64 * 96; i += 256) {
        int row = i / 96, c4 = (i - row * 96) * 4;
        float4 v = *(const float4*)(aev + (base + row) * 384 + c4);
        bf16x4 o = {(__bf16)v.x, (__bf16)v.y, (__bf16)v.z, (__bf16)v.w};
        *(bf16x4*)(sFeat + row * 400 + c4) = o;
    }
    __syncthreads();
    mlp_layer<10, 12, 400, 176, true>(sFeat, (const bf16x8*)bp1, b1, sAct1, t);
    __syncthreads();
    mlp_layer<8, 5, 176, 144, true>(sAct1, (const bf16x8*)bp2, b2, sAct2, t);
    __syncthreads();
    mlp_layer<6, 4, 144, 112, true>(sAct2, (const bf16x8*)bp3, b3, sAct3, t);
    __syncthreads();
    if (t < 64) {
        float acc = l4_dot(sAct3 + t * 112, W4);
        float chiv = softplusf_(acc + b4[0]);
        long atom = base + t;
        if (species[atom] == -1) chiv = 0.f;
        chi_out[atom] = chiv;
    }
}

// ---------------- per-molecule q / ESP / coulomb (256 threads) -------------
__global__ __launch_bounds__(256) void mol_kernel(
    const int* __restrict__ species, const float* __restrict__ coords,
    const float* __restrict__ netq, const float* __restrict__ chi,
    float* __restrict__ qv, float* __restrict__ esp, float* __restrict__ coul,
    float* __restrict__ o_species, float* __restrict__ o_q)
{
    const int m = blockIdx.x, t = threadIdx.x;
    const int j = t & 63, q4 = t >> 6;
    const int atom = m * 64 + j;
    __shared__ float sx[64], sy[64], sz[64], sq[64], ss2[64];
    __shared__ float sEsp[4][64];

    int s = species[atom];
    float pad = (s != -1) ? 1.0f : 0.0f;
    float chij = chi[atom];

    float cs = chij, na = pad;
#pragma unroll
    for (int o = 32; o > 0; o >>= 1) {
        cs += __shfl_xor(cs, o);
        na += __shfl_xor(na, o);
    }
    float qc = netq[m];
    float k_net = 1.0f + fabsf(qc) / cs;
    float chi_mean = cs / na;
    float k_p = (qc > 0.0f) ? k_net : 1.0f;
    float k_n = (qc < 0.0f) ? k_net : 1.0f;
    float qj = (-k_n * chij + k_p * chi_mean) * pad;

    float sg = c_SIGMA[s < 0 ? 0 : s];
    float x = coords[atom * 3 + 0], y = coords[atom * 3 + 1], z = coords[atom * 3 + 2];
    if (q4 == 0) { sx[j] = x; sy[j] = y; sz[j] = z; sq[j] = qj; ss2[j] = sg * sg; }
    __syncthreads();

    float s2j = sg * sg;
    float ej = 0.0f;
#pragma unroll
    for (int k = 0; k < 16; ++k) {
        int i = q4 * 16 + k;
        if (i == j) continue;
        float dx = sx[i] - x, dy = sy[i] - y, dz = sz[i] - z;
        float d = sqrtf(dx * dx + dy * dy + dz * dz + 1e-16f) * A0_INV;
        float ssum = fmaxf(ss2[i] + s2j, 1e-8f);
        float jij = erff(d * rsqrtf(2.0f * ssum)) / d;
        ej = fmaf(sq[i], jij, ej);
    }
    sEsp[q4][j] = ej;
    __syncthreads();
    if (q4 == 0) {
        float e = (sEsp[0][j] + sEsp[1][j]) + (sEsp[2][j] + sEsp[3][j]);
        e *= pad;
        float ce = qj * e;
#pragma unroll
        for (int o = 32; o > 0; o >>= 1) ce += __shfl_xor(ce, o);
        if (j == 0) coul[m] = 0.5f * ce;
        qv[atom] = qj;
        esp[atom] = e;
        o_species[atom] = (float)s;
        o_q[atom] = qj;
    }
}

// ---------------- species bucketing: deterministic, zero global atomics ----
__global__ __launch_bounds__(256) void bucket_count_kernel(
    const int* __restrict__ species, int* __restrict__ blockCounts,
    float* __restrict__ outat, int A)
{
    __shared__ int hist[8];
    const int t = threadIdx.x;
    if (t < 8) hist[t] = 0;
    __syncthreads();
    int a = blockIdx.x * 256 + t;
    if (a < A) {
        outat[a] = 0.0f;
        int s = species[a];
        if (s >= 0) atomicAdd(&hist[s], 1);
    }
    __syncthreads();
    if (t < 8) blockCounts[blockIdx.x * 8 + t] = hist[t];
}

// scan + build compact work list: workItems[i] = (e<<20)|startRow
__global__ void bucket_scan_kernel(int* __restrict__ blockCounts,
                                   int* __restrict__ counts, int* __restrict__ offs,
                                   int* __restrict__ workItems, int* __restrict__ workCount,
                                   int nBlocks)
{
    const int e = threadIdx.x;
    __shared__ int tot[8];
    if (e < 8) {
        int run = 0;
        for (int b = 0; b < nBlocks; ++b) {
            int c = blockCounts[b * 8 + e];
            blockCounts[b * 8 + e] = run;
            run += c;
        }
        tot[e] = run;
    }
    __syncthreads();
    if (e == 0) {
        int o = 0;
        for (int i = 0; i < 8; ++i) { offs[i] = o; counts[i] = tot[i]; o += tot[i]; }
        offs[8] = o;
    }
    __syncthreads();
    if (e < 8) {
        int pos = 0;
        for (int i = 0; i < e; ++i) pos += (tot[i] + 63) >> 6;
        int nt_e = (tot[e] + 63) >> 6;
        for (int k = 0; k < nt_e; ++k) workItems[pos + k] = (e << 20) | (k * 64);
        if (e == 7) workCount[0] = pos + nt_e;
    }
}

__global__ __launch_bounds__(256) void bucket_fill_kernel(
    const int* __restrict__ species, const int* __restrict__ blockCounts,
    const int* __restrict__ offs, int* __restrict__ bidx, int A)
{
    __shared__ int waveCnt[4][8];
    const int t = threadIdx.x, lane = t & 63, w = t >> 6;
    int a = blockIdx.x * 256 + t;
    int s = (a < A) ? species[a] : -1;
    unsigned long long mymask = 0;
#pragma unroll
    for (int e = 0; e < 8; ++e) {
        unsigned long long b = __ballot(s == e);
        if (lane == e) waveCnt[w][e] = (int)__popcll(b);
        if (s == e) mymask = b;
    }
    __syncthreads();
    if (s >= 0) {
        int prefix = 0;
        for (int w2 = 0; w2 < w; ++w2) prefix += waveCnt[w2][s];
        int rank = (int)__popcll(mymask & ((1ull << lane) - 1ull));
        bidx[offs[s] + blockCounts[blockIdx.x * 8 + s] + prefix + rank] = a;
    }
}

// ---------------- routed expert MLP: compact work list, 64 atoms / block ---
__global__ __launch_bounds__(256) void expert_mfma_kernel(
    const float* __restrict__ aev, const float* __restrict__ qv, const float* __restrict__ esp,
    const __bf16* __restrict__ bp1, const __bf16* __restrict__ bp2, const __bf16* __restrict__ bp3,
    const float* __restrict__ b1, const float* __restrict__ b2, const float* __restrict__ b3,
    const float* __restrict__ W4, const float* __restrict__ b4,
    const int* __restrict__ counts, const int* __restrict__ offs, const int* __restrict__ bidx,
    const int* __restrict__ workItems, const int* __restrict__ workCount,
    float* __restrict__ outat)
{
    const int bid = blockIdx.x;
    if (bid >= workCount[0]) return;
    const int wi = workItems[bid];
    const int e = wi >> 20;
    const int start = wi & 0xFFFFF;
    const int cnt = counts[e];

    __shared__ __align__(16) unsigned char smem[55296 + 22528];   // 76 KB
    __shared__ int said[64];
    __bf16* sFeat = (__bf16*)smem;            // [64][432] (416 used)
    __bf16* sAct1 = (__bf16*)(smem + 55296);  // [64][176]
    __bf16* sAct2 = (__bf16*)smem;            // [64][144]
    __bf16* sAct3 = (__bf16*)(smem + 18432);  // [64][112]
    const int t = threadIdx.x;

    if (t < 64) said[t] = (start + t < cnt) ? bidx[offs[e] + start + t] : -1;
    __syncthreads();

    // staging: 4 threads per row, said read once, 26 independent gathers each
    {
        const int row = t >> 2, quarter = t & 3;
        const int atom = said[row];
        const float* src = aev + (long)atom * 384;
#pragma unroll
        for (int k = 0; k < 26; ++k) {
            int c4 = (quarter * 26 + k) * 4;
            bf16x4 o = {(__bf16)0.f, (__bf16)0.f, (__bf16)0.f, (__bf16)0.f};
            if (atom >= 0) {
                if (c4 < 384) {
                    float4 v = *(const float4*)(src + c4);
                    o[0] = (__bf16)v.x; o[1] = (__bf16)v.y;
                    o[2] = (__bf16)v.z; o[3] = (__bf16)v.w;
                } else if (c4 == 384) {
                    o[0] = (__bf16)qv[atom]; o[1] = (__bf16)esp[atom];
                }
            }
            *(bf16x4*)(sFeat + row * 432 + c4) = o;
        }
    }
    __syncthreads();
    mlp_layer<10, 13, 432, 176, true>(sFeat, (const bf16x8*)bp1 + (size_t)e * 10 * 13 * 64,
                                      b1 + e * 160, sAct1, t);
    __syncthreads();
    mlp_layer<8, 5, 176, 144, true>(sAct1, (const bf16x8*)bp2 + (size_t)e * 8 * 5 * 64,
                                    b2 + e * 128, sAct2, t);
    __syncthreads();
    mlp_layer<6, 4, 144, 112, true>(sAct2, (const bf16x8*)bp3 + (size_t)e * 6 * 4 * 64,
                                    b3 + e * 96, sAct3, t);
    __syncthreads();
    if (t < 64) {
        int atom = said[t];
        if (atom >= 0) {
            float acc = l4_dot(sAct3 + t * 112, W4 + e * 96);
            outat[atom] = acc + b4[e];
        }
    }
}

// ---------------- per-molecule energy -----------------------------
__global__ __launch_bounds__(64) void energy_kernel(
    const float* __restrict__ outat, const float* __restrict__ coul,
    float* __restrict__ o_energy)
{
    int m = blockIdx.x, t = threadIdx.x;
    float v = outat[m * 64 + t];
#pragma unroll
    for (int o = 32; o > 0; o >>= 1) v += __shfl_xor(v, o);
    if (t == 0) o_energy[m] = v + coul[m];
}

extern "C" void kernel_launch(void* const* d_in, const int* in_sizes, int n_in,
                              void* d_out, int out_size, void* d_ws, size_t ws_size,
                              hipStream_t stream)
{
    const int*   species = (const int*)  d_in[0];
    const float* coords  = (const float*)d_in[1];
    const float* netq    = (const float*)d_in[2];
    const float* aev     = (const float*)d_in[3];
    const float* cW1 = (const float*)d_in[4];
    const float* cb1 = (const float*)d_in[5];
    const float* cW2 = (const float*)d_in[6];
    const float* cb2 = (const float*)d_in[7];
    const float* cW3 = (const float*)d_in[8];
    const float* cb3 = (const float*)d_in[9];
    const float* cW4 = (const float*)d_in[10];
    const float* cb4 = (const float*)d_in[11];
    const float* W1  = (const float*)d_in[12];
    const float* b1  = (const float*)d_in[13];
    const float* W2  = (const float*)d_in[14];
    const float* b2  = (const float*)d_in[15];
    const float* W3  = (const float*)d_in[16];
    const float* b3  = (const float*)d_in[17];
    const float* W4  = (const float*)d_in[18];
    const float* b4  = (const float*)d_in[19];

    const int N = in_sizes[2];          // 512
    const int n = in_sizes[0] / N;      // 64
    const int A = N * n;                // 32768
    const int nBlocks = (A + 255) / 256;
    const int maxWork = A / 64 + 8;     // 520

    // ---- workspace layout ----
    float* fbase   = (float*)d_ws;
    float* chi     = fbase;
    float* qv      = fbase + (size_t)A;
    float* esp     = fbase + (size_t)2 * A;
    float* outat   = fbase + (size_t)3 * A;
    float* coul    = fbase + (size_t)4 * A;
    int*   counts  = (int*)(coul + N);
    int*   offs    = counts + 8;
    int*   workCount = offs + 9;
    int*   workItems = workCount + 1;            // maxWork ints
    int*   blockCounts = workItems + maxWork;    // nBlocks*8 ints
    int*   bidx    = blockCounts + nBlocks * 8;
    uintptr_t p = ((uintptr_t)(bidx + A) + 15) & ~(uintptr_t)15;
    __bf16* bp_c1 = (__bf16*)p; p += (size_t)10 * 12 * 512 * 2;
    __bf16* bp_c2 = (__bf16*)p; p += (size_t)8  * 5  * 512 * 2;
    __bf16* bp_c3 = (__bf16*)p; p += (size_t)6  * 4  * 512 * 2;
    __bf16* bp_e1 = (__bf16*)p; p += (size_t)8 * 10 * 13 * 512 * 2;
    __bf16* bp_e2 = (__bf16*)p; p += (size_t)8 * 8  * 5  * 512 * 2;
    __bf16* bp_e3 = (__bf16*)p; p += (size_t)8 * 6  * 4  * 512 * 2;

    float* o_species = (float*)d_out;        // A elems (species as float)
    float* o_energy  = o_species + A;        // N elems
    float* o_q       = o_energy + N;         // A elems

    pack_all_kernel<<<(111104 + 255) / 256, 256, 0, stream>>>(
        cW1, cW2, cW3, W1, W2, W3, bp_c1, bp_c2, bp_c3, bp_e1, bp_e2, bp_e3);

    chi_mfma_kernel<<<A / 64, 256, 0, stream>>>(aev, species, bp_c1, bp_c2, bp_c3,
                                                cb1, cb2, cb3, cW4, cb4, chi);
    mol_kernel<<<N, 256, 0, stream>>>(species, coords, netq, chi, qv, esp, coul,
                                      (float*)d_out, o_q);
    bucket_count_kernel<<<nBlocks, 256, 0, stream>>>(species, blockCounts, outat, A);
    bucket_scan_kernel<<<1, 64, 0, stream>>>(blockCounts, counts, offs,
                                             workItems, workCount, nBlocks);
    bucket_fill_kernel<<<nBlocks, 256, 0, stream>>>(species, blockCounts, offs, bidx, A);
    expert_mfma_kernel<<<maxWork, 256, 0, stream>>>(aev, qv, esp, bp_e1, bp_e2, bp_e3,
                                                    b1, b2, b3, W4, b4,
                                                    counts, offs, bidx,
                                                    workItems, workCount, outat);
    energy_kernel<<<N, 64, 0, stream>>>(outat, coul, o_energy);
}

// Round 5
// 129.694 us; speedup vs baseline: 9.9447x; 1.0962x over previous
//
#include <hip/hip_runtime.h>
#include <math.h>

#define A0_INV (1.0f/0.529177249f)

typedef __bf16 bf16x8 __attribute__((ext_vector_type(8)));
typedef __bf16 bf16x4 __attribute__((ext_vector_type(4)));
typedef float  f32x4  __attribute__((ext_vector_type(4)));

__device__ __constant__ float c_SIGMA[8] = {
    0.5515909f, 1.8886297f, 1.3225029f, 1.2316629f,
    2.1884933f, 1.7750372f, 1.3677907f, 1.3820058f};

__device__ __forceinline__ float celu01(float x) {
    return x > 0.0f ? x : 0.1f * expm1f(x * 10.0f);
}
__device__ __forceinline__ float softplusf_(float x) {
    return fmaxf(x, 0.0f) + log1pf(expf(-fabsf(x)));
}

// ---- pack weights (K,OUT) f32 -> B-fragment order bf16: Bp[e][nt][kt][lane][8]
__device__ __forceinline__ void pack_one(int idx, const float* __restrict__ W,
                                         __bf16* __restrict__ Bp,
                                         int K, int OUT, int NT, int KT)
{
    int lane = idx & 63;
    int rest = idx >> 6;
    int kt = rest % KT; rest /= KT;
    int nt = rest % NT;
    int e  = rest / NT;
    int col = nt * 16 + (lane & 15);
    int k0  = kt * 32 + (lane >> 4) * 8;
    bf16x8 o;
#pragma unroll
    for (int j = 0; j < 8; ++j) {
        int k = k0 + j;
        float v = (k < K) ? W[((long)e * K + k) * OUT + col] : 0.0f;
        o[j] = (__bf16)v;
    }
    *((bf16x8*)Bp + idx) = o;
}

__global__ __launch_bounds__(256) void pack_all_kernel(
    const float* __restrict__ cW1, const float* __restrict__ cW2, const float* __restrict__ cW3,
    const float* __restrict__ W1,  const float* __restrict__ W2,  const float* __restrict__ W3,
    __bf16* bp_c1, __bf16* bp_c2, __bf16* bp_c3,
    __bf16* bp_e1, __bf16* bp_e2, __bf16* bp_e3)
{
    int idx = blockIdx.x * 256 + threadIdx.x;
    if      (idx <   7680) pack_one(idx,          cW1, bp_c1, 384, 160, 10, 12);
    else if (idx <  10240) pack_one(idx - 7680,   cW2, bp_c2, 160, 128,  8,  5);
    else if (idx <  11776) pack_one(idx - 10240,  cW3, bp_c3, 128,  96,  6,  4);
    else if (idx <  78336) pack_one(idx - 11776,  W1,  bp_e1, 386, 160, 10, 13);
    else if (idx <  98816) pack_one(idx - 78336,  W2,  bp_e2, 160, 128,  8,  5);
    else if (idx < 111104) pack_one(idx - 98816,  W3,  bp_e3, 128,  96,  6,  4);
}

// ---- one MFMA MLP layer over a 64-atom LDS tile, 1-deep B prefetch ----
// INS/OUTS are LDS row strides in bf16 elems (8*odd -> conflict-free b128 reads)
template<int NT, int KT, int INS, int OUTS, bool CELU>
__device__ __forceinline__ void mlp_layer(const __bf16* sIn, const bf16x8* __restrict__ Bp,
                                          const float* __restrict__ bias, __bf16* sOut, int tid)
{
    const int lane = tid & 63;
    const int wid  = tid >> 6;
    const int r16  = lane & 15;
    const int g    = lane >> 4;
    constexpr int NJ = (NT + 3) / 4;
    f32x4 acc[4][NJ];
#pragma unroll
    for (int mt = 0; mt < 4; ++mt)
#pragma unroll
        for (int j = 0; j < NJ; ++j)
            acc[mt][j] = (f32x4){0.f, 0.f, 0.f, 0.f};

    bf16x8 bcur[NJ], bnxt[NJ];
#pragma unroll
    for (int j = 0; j < NJ; ++j) {
        const int nt = wid + 4 * j;
        if (nt < NT) bcur[j] = Bp[(nt * KT) * 64 + lane];
    }
    for (int kt = 0; kt < KT; ++kt) {
        bf16x8 a[4];
#pragma unroll
        for (int mt = 0; mt < 4; ++mt)
            a[mt] = *(const bf16x8*)(sIn + (mt * 16 + r16) * INS + kt * 32 + g * 8);
        if (kt + 1 < KT) {
#pragma unroll
            for (int j = 0; j < NJ; ++j) {
                const int nt = wid + 4 * j;
                if (nt < NT) bnxt[j] = Bp[(nt * KT + kt + 1) * 64 + lane];
            }
        }
#pragma unroll
        for (int j = 0; j < NJ; ++j) {
            const int nt = wid + 4 * j;
            if (nt < NT) {
#pragma unroll
                for (int mt = 0; mt < 4; ++mt)
                    acc[mt][j] = __builtin_amdgcn_mfma_f32_16x16x32_bf16(a[mt], bcur[j], acc[mt][j], 0, 0, 0);
            }
        }
#pragma unroll
        for (int j = 0; j < NJ; ++j) bcur[j] = bnxt[j];
    }
#pragma unroll
    for (int j = 0; j < NJ; ++j) {
        const int nt = wid + 4 * j;
        if (nt < NT) {
            const float bb = bias[nt * 16 + r16];
#pragma unroll
            for (int mt = 0; mt < 4; ++mt)
#pragma unroll
                for (int r = 0; r < 4; ++r) {
                    float v = acc[mt][j][r] + bb;
                    if (CELU) v = celu01(v);
                    sOut[(mt * 16 + g * 4 + r) * OUTS + nt * 16 + r16] = (__bf16)v;
                }
        }
    }
}

// vectorized final-layer dot: h[96] (bf16, 16B-aligned) . w4[96] (f32)
__device__ __forceinline__ float l4_dot(const __bf16* __restrict__ h,
                                        const float* __restrict__ w4)
{
    float acc = 0.f;
#pragma unroll
    for (int u8 = 0; u8 < 12; ++u8) {
        bf16x8 hv = *(const bf16x8*)(h + u8 * 8);
        float4 wa = *(const float4*)(w4 + u8 * 8);
        float4 wb = *(const float4*)(w4 + u8 * 8 + 4);
        acc = fmaf((float)hv[0], wa.x, acc);
        acc = fmaf((float)hv[1], wa.y, acc);
        acc = fmaf((float)hv[2], wa.z, acc);
        acc = fmaf((float)hv[3], wa.w, acc);
        acc = fmaf((float)hv[4], wb.x, acc);
        acc = fmaf((float)hv[5], wb.y, acc);
        acc = fmaf((float)hv[6], wb.z, acc);
        acc = fmaf((float)hv[7], wb.w, acc);
    }
    return acc;
}

// ---------------- chi MLP (+ bf16 aev copy + species count/rank) -----------
__global__ __launch_bounds__(256) void chi_mfma_kernel(
    const float* __restrict__ aev, const int* __restrict__ species,
    const __bf16* __restrict__ bp1, const __bf16* __restrict__ bp2, const __bf16* __restrict__ bp3,
    const float* __restrict__ b1, const float* __restrict__ b2, const float* __restrict__ b3,
    const float* __restrict__ W4, const float* __restrict__ b4,
    float* __restrict__ chi_out, __bf16* __restrict__ aev16,
    int* __restrict__ blockCounts, int* __restrict__ rank)
{
    __shared__ __align__(16) unsigned char smem[50176 + 21504];   // 70 KB
    __bf16* sFeat = (__bf16*)smem;              // [64][392] (384 used)
    __bf16* sAct1 = (__bf16*)(smem + 50176);    // [64][168] (160 used)
    __bf16* sAct2 = (__bf16*)smem;              // [64][136] (alias dead sFeat)
    __bf16* sAct3 = (__bf16*)(smem + 17408);    // [64][104]
    const int t = threadIdx.x;
    const long base = (long)blockIdx.x * 64;

    if (aev16) {
        for (int i = t; i < 64 * 96; i += 256) {
            int row = i / 96, c4 = (i - row * 96) * 4;
            float4 v = *(const float4*)(aev + (base + row) * 384 + c4);
            bf16x4 o = {(__bf16)v.x, (__bf16)v.y, (__bf16)v.z, (__bf16)v.w};
            *(bf16x4*)(sFeat + row * 392 + c4) = o;
            *(bf16x4*)(aev16 + (base + row) * 384 + c4) = o;
        }
    } else {
        for (int i = t; i < 64 * 96; i += 256) {
            int row = i / 96, c4 = (i - row * 96) * 4;
            float4 v = *(const float4*)(aev + (base + row) * 384 + c4);
            bf16x4 o = {(__bf16)v.x, (__bf16)v.y, (__bf16)v.z, (__bf16)v.w};
            *(bf16x4*)(sFeat + row * 392 + c4) = o;
        }
    }
    __syncthreads();
    mlp_layer<10, 12, 392, 168, true>(sFeat, (const bf16x8*)bp1, b1, sAct1, t);
    __syncthreads();
    mlp_layer<8, 5, 168, 136, true>(sAct1, (const bf16x8*)bp2, b2, sAct2, t);
    __syncthreads();
    mlp_layer<6, 4, 136, 104, true>(sAct2, (const bf16x8*)bp3, b3, sAct3, t);
    __syncthreads();
    if (t < 64) {
        float acc = l4_dot(sAct3 + t * 104, W4);
        float chiv = softplusf_(acc + b4[0]);
        long atom = base + t;
        int s = species[atom];
        if (s == -1) chiv = 0.f;
        chi_out[atom] = chiv;
        // species histogram + in-block rank (wave 0 only, ballot-based)
        unsigned long long mym = 0;
#pragma unroll
        for (int e = 0; e < 8; ++e) {
            unsigned long long bm = __ballot(s == e);
            if (t == e) blockCounts[blockIdx.x * 8 + e] = (int)__popcll(bm);
            if (s == e) mym = bm;
        }
        if (s >= 0) rank[atom] = (int)__popcll(mym & ((1ull << t) - 1ull));
    }
}

// ---------------- per-molecule q / ESP / coulomb (256 threads) -------------
__global__ __launch_bounds__(256) void mol_kernel(
    const int* __restrict__ species, const float* __restrict__ coords,
    const float* __restrict__ netq, const float* __restrict__ chi,
    float* __restrict__ qv, float* __restrict__ esp, float* __restrict__ coul,
    float* __restrict__ o_species, float* __restrict__ o_q)
{
    const int m = blockIdx.x, t = threadIdx.x;
    const int j = t & 63, q4 = t >> 6;
    const int atom = m * 64 + j;
    __shared__ float sx[64], sy[64], sz[64], sq[64], ss2[64];
    __shared__ float sEsp[4][64];

    int s = species[atom];
    float pad = (s != -1) ? 1.0f : 0.0f;
    float chij = chi[atom];

    float cs = chij, na = pad;
#pragma unroll
    for (int o = 32; o > 0; o >>= 1) {
        cs += __shfl_xor(cs, o);
        na += __shfl_xor(na, o);
    }
    float qc = netq[m];
    float k_net = 1.0f + fabsf(qc) / cs;
    float chi_mean = cs / na;
    float k_p = (qc > 0.0f) ? k_net : 1.0f;
    float k_n = (qc < 0.0f) ? k_net : 1.0f;
    float qj = (-k_n * chij + k_p * chi_mean) * pad;

    float sg = c_SIGMA[s < 0 ? 0 : s];
    float x = coords[atom * 3 + 0], y = coords[atom * 3 + 1], z = coords[atom * 3 + 2];
    if (q4 == 0) { sx[j] = x; sy[j] = y; sz[j] = z; sq[j] = qj; ss2[j] = sg * sg; }
    __syncthreads();

    float s2j = sg * sg;
    float ej = 0.0f;
#pragma unroll
    for (int k = 0; k < 16; ++k) {
        int i = q4 * 16 + k;
        if (i == j) continue;
        float dx = sx[i] - x, dy = sy[i] - y, dz = sz[i] - z;
        float d = sqrtf(dx * dx + dy * dy + dz * dz + 1e-16f) * A0_INV;
        float ssum = fmaxf(ss2[i] + s2j, 1e-8f);
        float jij = erff(d * rsqrtf(2.0f * ssum)) / d;
        ej = fmaf(sq[i], jij, ej);
    }
    sEsp[q4][j] = ej;
    __syncthreads();
    if (q4 == 0) {
        float e = (sEsp[0][j] + sEsp[1][j]) + (sEsp[2][j] + sEsp[3][j]);
        e *= pad;
        float ce = qj * e;
#pragma unroll
        for (int o = 32; o > 0; o >>= 1) ce += __shfl_xor(ce, o);
        if (j == 0) coul[m] = 0.5f * ce;
        qv[atom] = qj;
        esp[atom] = e;
        o_species[atom] = (float)s;
        o_q[atom] = qj;
    }
}

// ---------------- scan (two-level) + work-list build -----------------------
__global__ void bucket_scan_kernel(int* __restrict__ blockCounts,
                                   int* __restrict__ counts, int* __restrict__ offs,
                                   int* __restrict__ workItems, int* __restrict__ workCount,
                                   int nb)
{
    __shared__ int segSum[8][8];   // [seg][species]
    __shared__ int tot[8];
    const int tid = threadIdx.x;   // 64 threads
    const int seg = tid >> 3, e = tid & 7;
    const int per = (nb + 7) / 8;
    const int b0 = seg * per, b1 = min(b0 + per, nb);
    int run = 0;
    for (int b = b0; b < b1; ++b) run += blockCounts[b * 8 + e];
    segSum[seg][e] = run;
    __syncthreads();
    if (tid < 8) {
        int r = 0;
        for (int s2 = 0; s2 < 8; ++s2) { int c = segSum[s2][tid]; segSum[s2][tid] = r; r += c; }
        tot[tid] = r;
    }
    __syncthreads();
    int runp = segSum[seg][e];
    for (int b = b0; b < b1; ++b) {
        int c = blockCounts[b * 8 + e];
        blockCounts[b * 8 + e] = runp;
        runp += c;
    }
    if (tid == 0) {
        int o = 0;
        for (int i = 0; i < 8; ++i) { offs[i] = o; counts[i] = tot[i]; o += tot[i]; }
        offs[8] = o;
    }
    if (tid < 8) {
        int pos = 0;
        for (int i = 0; i < tid; ++i) pos += (tot[i] + 63) >> 6;
        int nt_e = (tot[tid] + 63) >> 6;
        for (int k = 0; k < nt_e; ++k) workItems[pos + k] = (tid << 20) | (k * 64);
        if (tid == 7) workCount[0] = pos + nt_e;
    }
}

// ---------------- fill: scatter atom ids + zero-init outat -----------------
__global__ __launch_bounds__(256) void bucket_fill_kernel(
    const int* __restrict__ species, const int* __restrict__ blockCounts,
    const int* __restrict__ offs, const int* __restrict__ rank,
    int* __restrict__ bidx, float* __restrict__ outat, int A)
{
    int a = blockIdx.x * 256 + threadIdx.x;
    if (a < A) {
        outat[a] = 0.0f;
        int s = species[a];
        if (s >= 0)
            bidx[offs[s] + blockCounts[(a >> 6) * 8 + s] + rank[a]] = a;
    }
}

// ---------------- routed expert MLP: compact work list, 64 atoms / block ---
__global__ __launch_bounds__(256) void expert_mfma_kernel(
    const float* __restrict__ aev, const __bf16* __restrict__ aev16,
    const float* __restrict__ qv, const float* __restrict__ esp,
    const __bf16* __restrict__ bp1, const __bf16* __restrict__ bp2, const __bf16* __restrict__ bp3,
    const float* __restrict__ b1, const float* __restrict__ b2, const float* __restrict__ b3,
    const float* __restrict__ W4, const float* __restrict__ b4,
    const int* __restrict__ counts, const int* __restrict__ offs, const int* __restrict__ bidx,
    const int* __restrict__ workItems, const int* __restrict__ workCount,
    float* __restrict__ outat)
{
    const int bid = blockIdx.x;
    if (bid >= workCount[0]) return;
    const int wi = workItems[bid];
    const int e = wi >> 20;
    const int start = wi & 0xFFFFF;
    const int cnt = counts[e];

    __shared__ __align__(16) unsigned char smem[54272 + 21504];   // 74 KB
    __shared__ int said[64];
    __bf16* sFeat = (__bf16*)smem;            // [64][424] (384+2 used, pad zeroed to 416)
    __bf16* sAct1 = (__bf16*)(smem + 54272);  // [64][168]
    __bf16* sAct2 = (__bf16*)smem;            // [64][136]
    __bf16* sAct3 = (__bf16*)(smem + 17408);  // [64][104]
    const int t = threadIdx.x;

    if (t < 64) said[t] = (start + t < cnt) ? bidx[offs[e] + start + t] : -1;
    __syncthreads();

    if (aev16) {
        // coalesced: lanes cover consecutive 16B of the same gathered row
        for (int i = t; i < 64 * 48; i += 256) {
            int row = i / 48, c = (i - row * 48) * 8;
            int atom = said[row];
            bf16x8 v = {(__bf16)0.f, (__bf16)0.f, (__bf16)0.f, (__bf16)0.f,
                        (__bf16)0.f, (__bf16)0.f, (__bf16)0.f, (__bf16)0.f};
            if (atom >= 0) v = *(const bf16x8*)(aev16 + (long)atom * 384 + c);
            *(bf16x8*)(sFeat + row * 424 + c) = v;
        }
    } else {
        for (int i = t; i < 64 * 96; i += 256) {
            int row = i / 96, c4 = (i - row * 96) * 4;
            int atom = said[row];
            bf16x4 o = {(__bf16)0.f, (__bf16)0.f, (__bf16)0.f, (__bf16)0.f};
            if (atom >= 0) {
                float4 v = *(const float4*)(aev + (long)atom * 384 + c4);
                o[0] = (__bf16)v.x; o[1] = (__bf16)v.y;
                o[2] = (__bf16)v.z; o[3] = (__bf16)v.w;
            }
            *(bf16x4*)(sFeat + row * 424 + c4) = o;
        }
    }
    if (t < 64) {
        int atom = said[t];
        float a0 = 0.f, a1 = 0.f;
        if (atom >= 0) { a0 = qv[atom]; a1 = esp[atom]; }
        sFeat[t * 424 + 384] = (__bf16)a0;
        sFeat[t * 424 + 385] = (__bf16)a1;
        // zero K-pad 386..415 (MFMA reads up to KT*32=416; NaN*0 = NaN otherwise)
        for (int c = 386; c < 416; ++c) sFeat[t * 424 + c] = (__bf16)0.f;
    }
    __syncthreads();
    mlp_layer<10, 13, 424, 168, true>(sFeat, (const bf16x8*)bp1 + (size_t)e * 10 * 13 * 64,
                                      b1 + e * 160, sAct1, t);
    __syncthreads();
    mlp_layer<8, 5, 168, 136, true>(sAct1, (const bf16x8*)bp2 + (size_t)e * 8 * 5 * 64,
                                    b2 + e * 128, sAct2, t);
    __syncthreads();
    mlp_layer<6, 4, 136, 104, true>(sAct2, (const bf16x8*)bp3 + (size_t)e * 6 * 4 * 64,
                                    b3 + e * 96, sAct3, t);
    __syncthreads();
    if (t < 64) {
        int atom = said[t];
        if (atom >= 0) {
            float acc = l4_dot(sAct3 + t * 104, W4 + e * 96);
            outat[atom] = acc + b4[e];
        }
    }
}

// ---------------- per-molecule energy -----------------------------
__global__ __launch_bounds__(64) void energy_kernel(
    const float* __restrict__ outat, const float* __restrict__ coul,
    float* __restrict__ o_energy)
{
    int m = blockIdx.x, t = threadIdx.x;
    float v = outat[m * 64 + t];
#pragma unroll
    for (int o = 32; o > 0; o >>= 1) v += __shfl_xor(v, o);
    if (t == 0) o_energy[m] = v + coul[m];
}

extern "C" void kernel_launch(void* const* d_in, const int* in_sizes, int n_in,
                              void* d_out, int out_size, void* d_ws, size_t ws_size,
                              hipStream_t stream)
{
    const int*   species = (const int*)  d_in[0];
    const float* coords  = (const float*)d_in[1];
    const float* netq    = (const float*)d_in[2];
    const float* aev     = (const float*)d_in[3];
    const float* cW1 = (const float*)d_in[4];
    const float* cb1 = (const float*)d_in[5];
    const float* cW2 = (const float*)d_in[6];
    const float* cb2 = (const float*)d_in[7];
    const float* cW3 = (const float*)d_in[8];
    const float* cb3 = (const float*)d_in[9];
    const float* cW4 = (const float*)d_in[10];
    const float* cb4 = (const float*)d_in[11];
    const float* W1  = (const float*)d_in[12];
    const float* b1  = (const float*)d_in[13];
    const float* W2  = (const float*)d_in[14];
    const float* b2  = (const float*)d_in[15];
    const float* W3  = (const float*)d_in[16];
    const float* b3  = (const float*)d_in[17];
    const float* W4  = (const float*)d_in[18];
    const float* b4  = (const float*)d_in[19];

    const int N = in_sizes[2];          // 512
    const int n = in_sizes[0] / N;      // 64
    const int A = N * n;                // 32768
    const int nb64 = A / 64;            // 512 (64-atom blocks)
    const int maxWork = nb64 + 8;       // 520

    // ---- workspace layout ----
    float* fbase   = (float*)d_ws;
    float* chi     = fbase;
    float* qv      = fbase + (size_t)A;
    float* esp     = fbase + (size_t)2 * A;
    float* outat   = fbase + (size_t)3 * A;
    float* coul    = fbase + (size_t)4 * A;
    int*   counts  = (int*)(coul + N);
    int*   offs    = counts + 8;
    int*   workCount = offs + 9;
    int*   workItems = workCount + 1;            // maxWork ints
    int*   blockCounts = workItems + maxWork;    // nb64*8 ints
    int*   rank    = blockCounts + nb64 * 8;     // A ints
    int*   bidx    = rank + A;                   // A ints
    uintptr_t p = ((uintptr_t)(bidx + A) + 15) & ~(uintptr_t)15;
    __bf16* bp_c1 = (__bf16*)p; p += (size_t)10 * 12 * 512 * 2;
    __bf16* bp_c2 = (__bf16*)p; p += (size_t)8  * 5  * 512 * 2;
    __bf16* bp_c3 = (__bf16*)p; p += (size_t)6  * 4  * 512 * 2;
    __bf16* bp_e1 = (__bf16*)p; p += (size_t)8 * 10 * 13 * 512 * 2;
    __bf16* bp_e2 = (__bf16*)p; p += (size_t)8 * 8  * 5  * 512 * 2;
    __bf16* bp_e3 = (__bf16*)p; p += (size_t)8 * 6  * 4  * 512 * 2;
    p = (p + 15) & ~(uintptr_t)15;
    __bf16* aev16 = (__bf16*)p;
    size_t need = (p - (uintptr_t)d_ws) + (size_t)A * 384 * 2;
    if (ws_size < need) aev16 = nullptr;         // fp32 fallback path

    float* o_species = (float*)d_out;        // A elems (species as float)
    float* o_energy  = o_species + A;        // N elems
    float* o_q       = o_energy + N;         // A elems

    pack_all_kernel<<<(111104 + 255) / 256, 256, 0, stream>>>(
        cW1, cW2, cW3, W1, W2, W3, bp_c1, bp_c2, bp_c3, bp_e1, bp_e2, bp_e3);

    chi_mfma_kernel<<<nb64, 256, 0, stream>>>(aev, species, bp_c1, bp_c2, bp_c3,
                                              cb1, cb2, cb3, cW4, cb4, chi,
                                              aev16, blockCounts, rank);
    mol_kernel<<<N, 256, 0, stream>>>(species, coords, netq, chi, qv, esp, coul,
                                      (float*)d_out, o_q);
    bucket_scan_kernel<<<1, 64, 0, stream>>>(blockCounts, counts, offs,
                                             workItems, workCount, nb64);
    bucket_fill_kernel<<<(A + 255) / 256, 256, 0, stream>>>(species, blockCounts, offs,
                                                            rank, bidx, outat, A);
    expert_mfma_kernel<<<maxWork, 256, 0, stream>>>(aev, aev16, qv, esp,
                                                    bp_e1, bp_e2, bp_e3,
                                                    b1, b2, b3, W4, b4,
                                                    counts, offs, bidx,
                                                    workItems, workCount, outat);
    energy_kernel<<<N, 64, 0, stream>>>(outat, coul, o_energy);
}

// Round 6
// 91.561 us; speedup vs baseline: 14.0864x; 1.4165x over previous
//
#include <hip/hip_runtime.h>
#include <math.h>

#define A0_INV (1.0f/0.529177249f)

typedef __bf16 bf16x8 __attribute__((ext_vector_type(8)));
typedef __bf16 bf16x4 __attribute__((ext_vector_type(4)));
typedef float  f32x4  __attribute__((ext_vector_type(4)));

__device__ __constant__ float c_SIGMA[8] = {
    0.5515909f, 1.8886297f, 1.3225029f, 1.2316629f,
    2.1884933f, 1.7750372f, 1.3677907f, 1.3820058f};

__device__ __forceinline__ float celu01(float x) {
    return x > 0.0f ? x : 0.1f * (__expf(x * 10.0f) - 1.0f);
}
__device__ __forceinline__ float softplusf_(float x) {
    return fmaxf(x, 0.0f) + log1pf(__expf(-fabsf(x)));
}

// ---- pack weights (K,OUT) f32 -> B-fragment order bf16: Bp[e][nt][kt][lane][8]
__device__ __forceinline__ void pack_one(int idx, const float* __restrict__ W,
                                         __bf16* __restrict__ Bp,
                                         int K, int OUT, int NT, int KT)
{
    int lane = idx & 63;
    int rest = idx >> 6;
    int kt = rest % KT; rest /= KT;
    int nt = rest % NT;
    int e  = rest / NT;
    int col = nt * 16 + (lane & 15);
    int k0  = kt * 32 + (lane >> 4) * 8;
    bf16x8 o;
#pragma unroll
    for (int j = 0; j < 8; ++j) {
        int k = k0 + j;
        float v = (k < K) ? W[((long)e * K + k) * OUT + col] : 0.0f;
        o[j] = (__bf16)v;
    }
    *((bf16x8*)Bp + idx) = o;
}

__global__ __launch_bounds__(256) void pack_all_kernel(
    const float* __restrict__ cW1, const float* __restrict__ cW2, const float* __restrict__ cW3,
    const float* __restrict__ W1,  const float* __restrict__ W2,  const float* __restrict__ W3,
    __bf16* bp_c1, __bf16* bp_c2, __bf16* bp_c3,
    __bf16* bp_e1, __bf16* bp_e2, __bf16* bp_e3)
{
    int idx = blockIdx.x * 256 + threadIdx.x;
    if      (idx <   7680) pack_one(idx,          cW1, bp_c1, 384, 160, 10, 12);
    else if (idx <  10240) pack_one(idx - 7680,   cW2, bp_c2, 160, 128,  8,  5);
    else if (idx <  11776) pack_one(idx - 10240,  cW3, bp_c3, 128,  96,  6,  4);
    else if (idx <  78336) pack_one(idx - 11776,  W1,  bp_e1, 386, 160, 10, 13);
    else if (idx <  98816) pack_one(idx - 78336,  W2,  bp_e2, 160, 128,  8,  5);
    else if (idx < 111104) pack_one(idx - 98816,  W3,  bp_e3, 128,  96,  6,  4);
}

// ---- one MFMA MLP layer over a 64-atom LDS tile, 8 waves (2 Mw x 4 Nw) ----
// Wave (mw,nw): handles M-tiles {mw*2, mw*2+1}, N-tiles {nw, nw+4, nw+8}.
// 1-deep B prefetch. INS/OUTS strides in bf16 elems (8*odd -> low bank conflict).
template<int NT, int KT, int INS, int OUTS, bool CELU>
__device__ __forceinline__ void mlp_layer8(const __bf16* sIn, const bf16x8* __restrict__ Bp,
                                           const float* __restrict__ bias, __bf16* sOut, int tid)
{
    const int lane = tid & 63;
    const int wid  = tid >> 6;       // 0..7
    const int mw   = wid >> 2;       // 0..1
    const int nw   = wid & 3;        // 0..3
    const int r16  = lane & 15;
    const int g    = lane >> 4;
    constexpr int NJ = (NT + 3) / 4;
    f32x4 acc[2][NJ];
#pragma unroll
    for (int mi = 0; mi < 2; ++mi)
#pragma unroll
        for (int j = 0; j < NJ; ++j)
            acc[mi][j] = (f32x4){0.f, 0.f, 0.f, 0.f};

    bf16x8 bcur[NJ], bnxt[NJ];
#pragma unroll
    for (int j = 0; j < NJ; ++j) {
        const int nt = nw + 4 * j;
        if (nt < NT) bcur[j] = Bp[(nt * KT) * 64 + lane];
    }
    for (int kt = 0; kt < KT; ++kt) {
        bf16x8 a[2];
#pragma unroll
        for (int mi = 0; mi < 2; ++mi)
            a[mi] = *(const bf16x8*)(sIn + ((mw * 2 + mi) * 16 + r16) * INS + kt * 32 + g * 8);
        if (kt + 1 < KT) {
#pragma unroll
            for (int j = 0; j < NJ; ++j) {
                const int nt = nw + 4 * j;
                if (nt < NT) bnxt[j] = Bp[(nt * KT + kt + 1) * 64 + lane];
            }
        }
#pragma unroll
        for (int j = 0; j < NJ; ++j) {
            const int nt = nw + 4 * j;
            if (nt < NT) {
#pragma unroll
                for (int mi = 0; mi < 2; ++mi)
                    acc[mi][j] = __builtin_amdgcn_mfma_f32_16x16x32_bf16(a[mi], bcur[j], acc[mi][j], 0, 0, 0);
            }
        }
#pragma unroll
        for (int j = 0; j < NJ; ++j) bcur[j] = bnxt[j];
    }
#pragma unroll
    for (int j = 0; j < NJ; ++j) {
        const int nt = nw + 4 * j;
        if (nt < NT) {
            const float bb = bias[nt * 16 + r16];
#pragma unroll
            for (int mi = 0; mi < 2; ++mi)
#pragma unroll
                for (int r = 0; r < 4; ++r) {
                    float v = acc[mi][j][r] + bb;
                    if (CELU) v = celu01(v);
                    sOut[((mw * 2 + mi) * 16 + g * 4 + r) * OUTS + nt * 16 + r16] = (__bf16)v;
                }
        }
    }
}

// vectorized final-layer dot: h[96] (bf16, 16B-aligned) . w4[96] (f32)
__device__ __forceinline__ float l4_dot(const __bf16* __restrict__ h,
                                        const float* __restrict__ w4)
{
    float acc = 0.f;
#pragma unroll
    for (int u8 = 0; u8 < 12; ++u8) {
        bf16x8 hv = *(const bf16x8*)(h + u8 * 8);
        float4 wa = *(const float4*)(w4 + u8 * 8);
        float4 wb = *(const float4*)(w4 + u8 * 8 + 4);
        acc = fmaf((float)hv[0], wa.x, acc);
        acc = fmaf((float)hv[1], wa.y, acc);
        acc = fmaf((float)hv[2], wa.z, acc);
        acc = fmaf((float)hv[3], wa.w, acc);
        acc = fmaf((float)hv[4], wb.x, acc);
        acc = fmaf((float)hv[5], wb.y, acc);
        acc = fmaf((float)hv[6], wb.z, acc);
        acc = fmaf((float)hv[7], wb.w, acc);
    }
    return acc;
}

// ---------------- chi MLP (+ bf16 aev copy + species count/rank) -----------
__global__ __launch_bounds__(512) void chi_mfma_kernel(
    const float* __restrict__ aev, const int* __restrict__ species,
    const __bf16* __restrict__ bp1, const __bf16* __restrict__ bp2, const __bf16* __restrict__ bp3,
    const float* __restrict__ b1, const float* __restrict__ b2, const float* __restrict__ b3,
    const float* __restrict__ W4, const float* __restrict__ b4,
    float* __restrict__ chi_out, __bf16* __restrict__ aev16,
    int* __restrict__ blockCounts, int* __restrict__ rank)
{
    __shared__ __align__(16) unsigned char smem[50176 + 21504];   // 70 KB
    __bf16* sFeat = (__bf16*)smem;              // [64][392] (384 used)
    __bf16* sAct1 = (__bf16*)(smem + 50176);    // [64][168] (160 used)
    __bf16* sAct2 = (__bf16*)smem;              // [64][136] (alias dead sFeat)
    __bf16* sAct3 = (__bf16*)(smem + 17408);    // [64][104]
    const int t = threadIdx.x;
    const long base = (long)blockIdx.x * 64;

    if (aev16) {
        for (int i = t; i < 64 * 96; i += 512) {
            int row = i / 96, c4 = (i - row * 96) * 4;
            float4 v = *(const float4*)(aev + (base + row) * 384 + c4);
            bf16x4 o = {(__bf16)v.x, (__bf16)v.y, (__bf16)v.z, (__bf16)v.w};
            *(bf16x4*)(sFeat + row * 392 + c4) = o;
            *(bf16x4*)(aev16 + (base + row) * 384 + c4) = o;
        }
    } else {
        for (int i = t; i < 64 * 96; i += 512) {
            int row = i / 96, c4 = (i - row * 96) * 4;
            float4 v = *(const float4*)(aev + (base + row) * 384 + c4);
            bf16x4 o = {(__bf16)v.x, (__bf16)v.y, (__bf16)v.z, (__bf16)v.w};
            *(bf16x4*)(sFeat + row * 392 + c4) = o;
        }
    }
    __syncthreads();
    mlp_layer8<10, 12, 392, 168, true>(sFeat, (const bf16x8*)bp1, b1, sAct1, t);
    __syncthreads();
    mlp_layer8<8, 5, 168, 136, true>(sAct1, (const bf16x8*)bp2, b2, sAct2, t);
    __syncthreads();
    mlp_layer8<6, 4, 136, 104, true>(sAct2, (const bf16x8*)bp3, b3, sAct3, t);
    __syncthreads();
    if (t < 64) {
        float acc = l4_dot(sAct3 + t * 104, W4);
        float chiv = softplusf_(acc + b4[0]);
        long atom = base + t;
        int s = species[atom];
        if (s == -1) chiv = 0.f;
        chi_out[atom] = chiv;
        // species histogram + in-block rank (wave 0 only, ballot-based)
        unsigned long long mym = 0;
#pragma unroll
        for (int e = 0; e < 8; ++e) {
            unsigned long long bm = __ballot(s == e);
            if (t == e) blockCounts[blockIdx.x * 8 + e] = (int)__popcll(bm);
            if (s == e) mym = bm;
        }
        if (s >= 0) rank[atom] = (int)__popcll(mym & ((1ull << t) - 1ull));
    }
}

// ---------------- per-molecule q / ESP / coulomb (256 threads) -------------
__global__ __launch_bounds__(256) void mol_kernel(
    const int* __restrict__ species, const float* __restrict__ coords,
    const float* __restrict__ netq, const float* __restrict__ chi,
    float* __restrict__ qv, float* __restrict__ esp, float* __restrict__ coul,
    float* __restrict__ o_species, float* __restrict__ o_q)
{
    const int m = blockIdx.x, t = threadIdx.x;
    const int j = t & 63, q4 = t >> 6;
    const int atom = m * 64 + j;
    __shared__ float sx[64], sy[64], sz[64], sq[64], ss2[64];
    __shared__ float sEsp[4][64];

    int s = species[atom];
    float pad = (s != -1) ? 1.0f : 0.0f;
    float chij = chi[atom];

    float cs = chij, na = pad;
#pragma unroll
    for (int o = 32; o > 0; o >>= 1) {
        cs += __shfl_xor(cs, o);
        na += __shfl_xor(na, o);
    }
    float qc = netq[m];
    float k_net = 1.0f + fabsf(qc) / cs;
    float chi_mean = cs / na;
    float k_p = (qc > 0.0f) ? k_net : 1.0f;
    float k_n = (qc < 0.0f) ? k_net : 1.0f;
    float qj = (-k_n * chij + k_p * chi_mean) * pad;

    float sg = c_SIGMA[s < 0 ? 0 : s];
    float x = coords[atom * 3 + 0], y = coords[atom * 3 + 1], z = coords[atom * 3 + 2];
    if (q4 == 0) { sx[j] = x; sy[j] = y; sz[j] = z; sq[j] = qj; ss2[j] = sg * sg; }
    __syncthreads();

    float s2j = sg * sg;
    float ej = 0.0f;
#pragma unroll
    for (int k = 0; k < 16; ++k) {
        int i = q4 * 16 + k;
        if (i == j) continue;
        float dx = sx[i] - x, dy = sy[i] - y, dz = sz[i] - z;
        float d = sqrtf(dx * dx + dy * dy + dz * dz + 1e-16f) * A0_INV;
        float ssum = fmaxf(ss2[i] + s2j, 1e-8f);
        float jij = erff(d * rsqrtf(2.0f * ssum)) / d;
        ej = fmaf(sq[i], jij, ej);
    }
    sEsp[q4][j] = ej;
    __syncthreads();
    if (q4 == 0) {
        float e = (sEsp[0][j] + sEsp[1][j]) + (sEsp[2][j] + sEsp[3][j]);
        e *= pad;
        float ce = qj * e;
#pragma unroll
        for (int o = 32; o > 0; o >>= 1) ce += __shfl_xor(ce, o);
        if (j == 0) coul[m] = 0.5f * ce;
        qv[atom] = qj;
        esp[atom] = e;
        o_species[atom] = (float)s;
        o_q[atom] = qj;
    }
}

// ---------------- scan (two-level) + work-list build -----------------------
__global__ void bucket_scan_kernel(int* __restrict__ blockCounts,
                                   int* __restrict__ counts, int* __restrict__ offs,
                                   int* __restrict__ workItems, int* __restrict__ workCount,
                                   int nb)
{
    __shared__ int segSum[8][8];   // [seg][species]
    __shared__ int tot[8];
    const int tid = threadIdx.x;   // 64 threads
    const int seg = tid >> 3, e = tid & 7;
    const int per = (nb + 7) / 8;
    const int b0 = seg * per, b1 = min(b0 + per, nb);
    int run = 0;
    for (int b = b0; b < b1; ++b) run += blockCounts[b * 8 + e];
    segSum[seg][e] = run;
    __syncthreads();
    if (tid < 8) {
        int r = 0;
        for (int s2 = 0; s2 < 8; ++s2) { int c = segSum[s2][tid]; segSum[s2][tid] = r; r += c; }
        tot[tid] = r;
    }
    __syncthreads();
    int runp = segSum[seg][e];
    for (int b = b0; b < b1; ++b) {
        int c = blockCounts[b * 8 + e];
        blockCounts[b * 8 + e] = runp;
        runp += c;
    }
    if (tid == 0) {
        int o = 0;
        for (int i = 0; i < 8; ++i) { offs[i] = o; counts[i] = tot[i]; o += tot[i]; }
        offs[8] = o;
    }
    if (tid < 8) {
        int pos = 0;
        for (int i = 0; i < tid; ++i) pos += (tot[i] + 63) >> 6;
        int nt_e = (tot[tid] + 63) >> 6;
        for (int k = 0; k < nt_e; ++k) workItems[pos + k] = (tid << 20) | (k * 64);
        if (tid == 7) workCount[0] = pos + nt_e;
    }
}

// ---------------- fill: scatter atom ids + zero-init outat -----------------
__global__ __launch_bounds__(256) void bucket_fill_kernel(
    const int* __restrict__ species, const int* __restrict__ blockCounts,
    const int* __restrict__ offs, const int* __restrict__ rank,
    int* __restrict__ bidx, float* __restrict__ outat, int A)
{
    int a = blockIdx.x * 256 + threadIdx.x;
    if (a < A) {
        outat[a] = 0.0f;
        int s = species[a];
        if (s >= 0)
            bidx[offs[s] + blockCounts[(a >> 6) * 8 + s] + rank[a]] = a;
    }
}

// ---------------- routed expert MLP: compact work list, 64 atoms / block ---
__global__ __launch_bounds__(512) void expert_mfma_kernel(
    const float* __restrict__ aev, const __bf16* __restrict__ aev16,
    const float* __restrict__ qv, const float* __restrict__ esp,
    const __bf16* __restrict__ bp1, const __bf16* __restrict__ bp2, const __bf16* __restrict__ bp3,
    const float* __restrict__ b1, const float* __restrict__ b2, const float* __restrict__ b3,
    const float* __restrict__ W4, const float* __restrict__ b4,
    const int* __restrict__ counts, const int* __restrict__ offs, const int* __restrict__ bidx,
    const int* __restrict__ workItems, const int* __restrict__ workCount,
    float* __restrict__ outat)
{
    const int bid = blockIdx.x;
    if (bid >= workCount[0]) return;
    const int wi = workItems[bid];
    const int e = wi >> 20;
    const int start = wi & 0xFFFFF;
    const int cnt = counts[e];

    __shared__ __align__(16) unsigned char smem[54272 + 21504];   // 74 KB
    __shared__ int said[64];
    __bf16* sFeat = (__bf16*)smem;            // [64][424] (384+2 used, pad zeroed to 416)
    __bf16* sAct1 = (__bf16*)(smem + 54272);  // [64][168]
    __bf16* sAct2 = (__bf16*)smem;            // [64][136]
    __bf16* sAct3 = (__bf16*)(smem + 17408);  // [64][104]
    const int t = threadIdx.x;

    if (t < 64) said[t] = (start + t < cnt) ? bidx[offs[e] + start + t] : -1;
    __syncthreads();

    if (aev16) {
        // coalesced: lanes cover consecutive 16B of the same gathered row
        for (int i = t; i < 64 * 48; i += 512) {
            int row = i / 48, c = (i - row * 48) * 8;
            int atom = said[row];
            bf16x8 v = {(__bf16)0.f, (__bf16)0.f, (__bf16)0.f, (__bf16)0.f,
                        (__bf16)0.f, (__bf16)0.f, (__bf16)0.f, (__bf16)0.f};
            if (atom >= 0) v = *(const bf16x8*)(aev16 + (long)atom * 384 + c);
            *(bf16x8*)(sFeat + row * 424 + c) = v;
        }
    } else {
        for (int i = t; i < 64 * 96; i += 512) {
            int row = i / 96, c4 = (i - row * 96) * 4;
            int atom = said[row];
            bf16x4 o = {(__bf16)0.f, (__bf16)0.f, (__bf16)0.f, (__bf16)0.f};
            if (atom >= 0) {
                float4 v = *(const float4*)(aev + (long)atom * 384 + c4);
                o[0] = (__bf16)v.x; o[1] = (__bf16)v.y;
                o[2] = (__bf16)v.z; o[3] = (__bf16)v.w;
            }
            *(bf16x4*)(sFeat + row * 424 + c4) = o;
        }
    }
    if (t < 64) {
        int atom = said[t];
        float a0 = 0.f, a1 = 0.f;
        if (atom >= 0) { a0 = qv[atom]; a1 = esp[atom]; }
        sFeat[t * 424 + 384] = (__bf16)a0;
        sFeat[t * 424 + 385] = (__bf16)a1;
        // zero K-pad 386..415 (MFMA reads up to KT*32=416)
        for (int c = 386; c < 416; ++c) sFeat[t * 424 + c] = (__bf16)0.f;
    }
    __syncthreads();
    mlp_layer8<10, 13, 424, 168, true>(sFeat, (const bf16x8*)bp1 + (size_t)e * 10 * 13 * 64,
                                       b1 + e * 160, sAct1, t);
    __syncthreads();
    mlp_layer8<8, 5, 168, 136, true>(sAct1, (const bf16x8*)bp2 + (size_t)e * 8 * 5 * 64,
                                     b2 + e * 128, sAct2, t);
    __syncthreads();
    mlp_layer8<6, 4, 136, 104, true>(sAct2, (const bf16x8*)bp3 + (size_t)e * 6 * 4 * 64,
                                     b3 + e * 96, sAct3, t);
    __syncthreads();
    if (t < 64) {
        int atom = said[t];
        if (atom >= 0) {
            float acc = l4_dot(sAct3 + t * 104, W4 + e * 96);
            outat[atom] = acc + b4[e];
        }
    }
}

// ---------------- per-molecule energy -----------------------------
__global__ __launch_bounds__(64) void energy_kernel(
    const float* __restrict__ outat, const float* __restrict__ coul,
    float* __restrict__ o_energy)
{
    int m = blockIdx.x, t = threadIdx.x;
    float v = outat[m * 64 + t];
#pragma unroll
    for (int o = 32; o > 0; o >>= 1) v += __shfl_xor(v, o);
    if (t == 0) o_energy[m] = v + coul[m];
}

extern "C" void kernel_launch(void* const* d_in, const int* in_sizes, int n_in,
                              void* d_out, int out_size, void* d_ws, size_t ws_size,
                              hipStream_t stream)
{
    const int*   species = (const int*)  d_in[0];
    const float* coords  = (const float*)d_in[1];
    const float* netq    = (const float*)d_in[2];
    const float* aev     = (const float*)d_in[3];
    const float* cW1 = (const float*)d_in[4];
    const float* cb1 = (const float*)d_in[5];
    const float* cW2 = (const float*)d_in[6];
    const float* cb2 = (const float*)d_in[7];
    const float* cW3 = (const float*)d_in[8];
    const float* cb3 = (const float*)d_in[9];
    const float* cW4 = (const float*)d_in[10];
    const float* cb4 = (const float*)d_in[11];
    const float* W1  = (const float*)d_in[12];
    const float* b1  = (const float*)d_in[13];
    const float* W2  = (const float*)d_in[14];
    const float* b2  = (const float*)d_in[15];
    const float* W3  = (const float*)d_in[16];
    const float* b3  = (const float*)d_in[17];
    const float* W4  = (const float*)d_in[18];
    const float* b4  = (const float*)d_in[19];

    const int N = in_sizes[2];          // 512
    const int n = in_sizes[0] / N;      // 64
    const int A = N * n;                // 32768
    const int nb64 = A / 64;            // 512 (64-atom blocks)
    const int maxWork = nb64 + 8;       // 520

    // ---- workspace layout ----
    float* fbase   = (float*)d_ws;
    float* chi     = fbase;
    float* qv      = fbase + (size_t)A;
    float* esp     = fbase + (size_t)2 * A;
    float* outat   = fbase + (size_t)3 * A;
    float* coul    = fbase + (size_t)4 * A;
    int*   counts  = (int*)(coul + N);
    int*   offs    = counts + 8;
    int*   workCount = offs + 9;
    int*   workItems = workCount + 1;            // maxWork ints
    int*   blockCounts = workItems + maxWork;    // nb64*8 ints
    int*   rank    = blockCounts + nb64 * 8;     // A ints
    int*   bidx    = rank + A;                   // A ints
    uintptr_t p = ((uintptr_t)(bidx + A) + 15) & ~(uintptr_t)15;
    __bf16* bp_c1 = (__bf16*)p; p += (size_t)10 * 12 * 512 * 2;
    __bf16* bp_c2 = (__bf16*)p; p += (size_t)8  * 5  * 512 * 2;
    __bf16* bp_c3 = (__bf16*)p; p += (size_t)6  * 4  * 512 * 2;
    __bf16* bp_e1 = (__bf16*)p; p += (size_t)8 * 10 * 13 * 512 * 2;
    __bf16* bp_e2 = (__bf16*)p; p += (size_t)8 * 8  * 5  * 512 * 2;
    __bf16* bp_e3 = (__bf16*)p; p += (size_t)8 * 6  * 4  * 512 * 2;
    p = (p + 15) & ~(uintptr_t)15;
    __bf16* aev16 = (__bf16*)p;
    size_t need = (p - (uintptr_t)d_ws) + (size_t)A * 384 * 2;
    if (ws_size < need) aev16 = nullptr;         // fp32 fallback path

    float* o_species = (float*)d_out;        // A elems (species as float)
    float* o_energy  = o_species + A;        // N elems
    float* o_q       = o_energy + N;         // A elems

    pack_all_kernel<<<(111104 + 255) / 256, 256, 0, stream>>>(
        cW1, cW2, cW3, W1, W2, W3, bp_c1, bp_c2, bp_c3, bp_e1, bp_e2, bp_e3);

    chi_mfma_kernel<<<nb64, 512, 0, stream>>>(aev, species, bp_c1, bp_c2, bp_c3,
                                              cb1, cb2, cb3, cW4, cb4, chi,
                                              aev16, blockCounts, rank);
    mol_kernel<<<N, 256, 0, stream>>>(species, coords, netq, chi, qv, esp, coul,
                                      (float*)d_out, o_q);
    bucket_scan_kernel<<<1, 64, 0, stream>>>(blockCounts, counts, offs,
                                             workItems, workCount, nb64);
    bucket_fill_kernel<<<(A + 255) / 256, 256, 0, stream>>>(species, blockCounts, offs,
                                                            rank, bidx, outat, A);
    expert_mfma_kernel<<<maxWork, 512, 0, stream>>>(aev, aev16, qv, esp,
                                                    bp_e1, bp_e2, bp_e3,
                                                    b1, b2, b3, W4, b4,
                                                    counts, offs, bidx,
                                                    workItems, workCount, outat);
    energy_kernel<<<N, 64, 0, stream>>>(outat, coul, o_energy);
}